// Round 1
// baseline (973.885 us; speedup 1.0000x reference)
//
#include <hip/hip_runtime.h>

#define CHUNKS 512
#define CHUNK_L 96
#define WARM 96

__device__ __forceinline__ float rcp_(float x){ return __builtin_amdgcn_rcpf(x); }
// sigmoid(z) = 1/(1+e^-z); tanh(z) = 1 - 2/(1+e^{2z})  (graceful at +-inf)
__device__ __forceinline__ float tanh_(float z){ return 1.f - 2.f*rcp_(1.f + __expf(2.f*z)); }

// ---------------- kernel 0: pack conv center-column weights into ws ----------------
// Layout: Wp[i][d][o] contiguous; L1 at 0 (50*3*100), L2 at 15000 (100*3*100), L3 at 45000 (100*3*50)
__global__ void pack_weights(const float* __restrict__ Wf1, const float* __restrict__ Wf2,
                             const float* __restrict__ Wf3, float* __restrict__ ws)
{
  const int t = blockIdx.x*256 + threadIdx.x;
  if (t < 15000){
    const int o = t % 100, rest = t/100, d = rest%3, i = rest/3;
    ws[t] = Wf1[((o*50 + i)*3 + d)*3 + 1];
  } else if (t < 45000){
    const int u = t-15000, o = u%100, rest = u/100, d = rest%3, i = rest/3;
    ws[t] = Wf2[((o*100 + i)*3 + d)*3 + 1];
  } else if (t < 60000){
    const int u = t-45000, o = u%50, rest = u/50, d = rest%3, i = rest/3;
    ws[t] = Wf3[((o*100 + i)*3 + d)*3 + 1];
  }
}

// ---------------- kernel 1: chunked LSTM scan (warm-up approximation) ----------------
// Phase A (t<200): thread = (node an, gate-group ag in {i,f,g,o}), 6 gate rows each,
//                  weights held in registers. Phase B (all t): state update, c in registers.
__global__ __launch_bounds__(256,2) void lstm_kernel(
    const float* __restrict__ X, const float* __restrict__ Wih,
    const float* __restrict__ Whh, const float* __restrict__ bih,
    const float* __restrict__ bhh, float* __restrict__ al)
{
  __shared__ float h_s[50][8];
  __shared__ float g_s[50][25];
  const int t = threadIdx.x;
  const int c = blockIdx.x;
  const int s_begin = c*CHUNK_L;
  const int s_start = (s_begin >= WARM) ? (s_begin - WARM) : 0;
  const int s_end = s_begin + CHUNK_L;

  const bool isA = (t < 200);
  const int an = t % 50;
  const int ag = t / 50;   // 0:i 1:f 2:g 3:o for t<200

  float wih[6][12], whh[6][6], bs[6];
  if (isA){
    #pragma unroll
    for (int j=0;j<6;j++){
      const int r = ag*6 + j;
      #pragma unroll
      for (int k=0;k<12;k++) wih[j][k] = Wih[r*12+k];
      #pragma unroll
      for (int k=0;k<6;k++)  whh[j][k] = Whh[r*6+k];
      bs[j] = bih[r] + bhh[r];
    }
  }

  const int bn1 = t/6, bj1 = t%6;           // state elem e1 = t  (< 300 always)
  const int e2 = t + 256;
  const bool hasE2 = (e2 < 300);
  const int bn2 = e2/6, bj2 = e2%6;
  float c1 = 0.f, c2 = 0.f;

  for (int idx=t; idx<50*8; idx+=256) ((float*)h_s)[idx] = 0.f;
  __syncthreads();

  float4 xv0, xv1, xv2;
  float4 xn0 = {0,0,0,0}, xn1 = {0,0,0,0}, xn2 = {0,0,0,0};
  if (isA){
    const float4* xp = (const float4*)(X + (size_t)s_start*600 + an*12);
    xv0 = xp[0]; xv1 = xp[1]; xv2 = xp[2];
  }

  for (int s = s_start; s < s_end; ++s){
    if (isA){
      const float xr[12] = {xv0.x,xv0.y,xv0.z,xv0.w, xv1.x,xv1.y,xv1.z,xv1.w,
                            xv2.x,xv2.y,xv2.z,xv2.w};
      const float4 h03 = *(const float4*)&h_s[an][0];
      const float2 h45 = *(const float2*)&h_s[an][4];
      const float hr[6] = {h03.x,h03.y,h03.z,h03.w,h45.x,h45.y};
      #pragma unroll
      for (int j=0;j<6;j++){
        float a = bs[j];
        #pragma unroll
        for (int k=0;k<12;k++) a += wih[j][k]*xr[k];
        #pragma unroll
        for (int k=0;k<6;k++)  a += whh[j][k]*hr[k];
        // unified activation: ag==2 -> tanh(a)=2*sigm(2a)-1, else sigm(a); one exp+rcp, no divergence
        const float zz = (ag==2) ? (a+a) : a;
        const float r = rcp_(1.f + __expf(-zz));
        g_s[an][ag*6+j] = (ag==2) ? (r+r-1.f) : r;
      }
      if (s+1 < s_end){   // prefetch next x; completes during phase B
        const float4* xp = (const float4*)(X + (size_t)(s+1)*600 + an*12);
        xn0 = xp[0]; xn1 = xp[1]; xn2 = xp[2];
      }
    }
    __syncthreads();
    {
      const float gi = g_s[bn1][bj1], gf = g_s[bn1][6+bj1],
                  gg = g_s[bn1][12+bj1], go = g_s[bn1][18+bj1];
      c1 = gf*c1 + gi*gg;
      const float hn = tanh_(go * tanh_(c1));
      h_s[bn1][bj1] = hn;
      float hn2 = 0.f;
      if (hasE2){
        const float gi2 = g_s[bn2][bj2], gf2 = g_s[bn2][6+bj2],
                    gg2 = g_s[bn2][12+bj2], go2 = g_s[bn2][18+bj2];
        c2 = gf2*c2 + gi2*gg2;
        hn2 = tanh_(go2 * tanh_(c2));
        h_s[bn2][bj2] = hn2;
      }
      if (s >= s_begin){
        al[(size_t)s*300 + t] = hn;
        if (hasE2) al[(size_t)s*300 + e2] = hn2;
      }
    }
    __syncthreads();
    if (isA){ xv0=xn0; xv1=xn1; xv2=xn2; }
  }
}

// ---------------- kernel 2: fused conv x3 + lean, in-place on d_out ----------------
template<bool P>
__device__ __forceinline__ float wfetch(const float* __restrict__ W, int I, int O,
                                        int i, int d, int o){
  return P ? W[(i*3+d)*O + o] : W[((o*I + i)*3 + d)*3 + 1];
}

// in/out: LDS [8][100][8]; slots y=0..5 data, 6..7 permanently zero (right pad).
// Left pad handled by skipping the y=0,d=0 term.
template<int NS, bool P>
__device__ void conv_layer(const float (* __restrict__ in)[100][8],
                           float (* __restrict__ outb)[100][8],
                           int I, int O, const float* __restrict__ W,
                           const float* __restrict__ bias, int o, int s0)
{
  float acc[NS][6];
  const float b = bias[o];
  #pragma unroll
  for (int s=0;s<NS;s++)
    #pragma unroll
    for (int y=0;y<6;y++) acc[s][y]=b;
  for (int i=0;i<I;i++){
    const float w0 = wfetch<P>(W,I,O,i,0,o);
    const float w1 = wfetch<P>(W,I,O,i,1,o);
    const float w2 = wfetch<P>(W,I,O,i,2,o);
    #pragma unroll
    for (int s=0;s<NS;s++){
      const float4 r0 = *(const float4*)&in[s0+s][i][0];
      const float4 r1 = *(const float4*)&in[s0+s][i][4];   // r1.z == 0 (pad)
      acc[s][0] += w1*r0.x + w2*r0.y;
      acc[s][1] += w0*r0.x + w1*r0.y + w2*r0.z;
      acc[s][2] += w0*r0.y + w1*r0.z + w2*r0.w;
      acc[s][3] += w0*r0.z + w1*r0.w + w2*r1.x;
      acc[s][4] += w0*r0.w + w1*r1.x + w2*r1.y;
      acc[s][5] += w0*r1.x + w1*r1.y;
    }
  }
  #pragma unroll
  for (int s=0;s<NS;s++){
    float4 v0; float2 v1;
    v0.x = fmaxf(acc[s][0],0.f); v0.y = fmaxf(acc[s][1],0.f);
    v0.z = fmaxf(acc[s][2],0.f); v0.w = fmaxf(acc[s][3],0.f);
    v1.x = fmaxf(acc[s][4],0.f); v1.y = fmaxf(acc[s][5],0.f);
    *(float4*)&outb[s0+s][o][0] = v0;
    *(float2*)&outb[s0+s][o][4] = v1;
  }
}

template<bool P>
__global__ __launch_bounds__(256,1) void conv_kernel(
    float* __restrict__ io,
    const float* __restrict__ W1, const float* __restrict__ b1,
    const float* __restrict__ W2, const float* __restrict__ b2,
    const float* __restrict__ W3, const float* __restrict__ b3,
    const float* __restrict__ Wl, const float* __restrict__ bl)
{
  __shared__ float A[8][100][8];
  __shared__ float B[8][100][8];
  const int t = threadIdx.x;
  const size_t base = (size_t)blockIdx.x * 8 * 300;

  for (int idx=t; idx<8*100; idx+=256){
    const int s = idx/100, ch = idx%100;
    A[s][ch][6]=0.f; A[s][ch][7]=0.f;
    B[s][ch][6]=0.f; B[s][ch][7]=0.f;
  }
  for (int idx=t; idx<2400; idx+=256){
    const float v = io[base + idx];
    const int s = idx/300, rr = idx%300;
    A[s][rr/6][rr%6] = v;
  }
  __syncthreads();

  const int w = t>>6, lane = t&63;
  {
    const int sh = w>>1, o = (w&1)*50 + lane;
    if (lane < 50) conv_layer<4,P>(A, B, 50, 100, W1, b1, o, sh*4);
  }
  __syncthreads();
  {
    const int sh = w>>1, o = (w&1)*50 + lane;
    if (lane < 50) conv_layer<4,P>(B, A, 100, 100, W2, b2, o, sh*4);
  }
  __syncthreads();
  {
    if (lane < 50) conv_layer<2,P>(A, B, 100, 50, W3, b3, lane, w*2);
  }
  __syncthreads();
  for (int idx=t; idx<2400; idx+=256){
    const int s = idx/300, rr = idx%300, n = rr/6, j = rr%6;
    const float4 r0 = *(const float4*)&B[s][n][0];
    const float2 r1 = *(const float2*)&B[s][n][4];
    io[base + idx] = bl[j] + Wl[j*6+0]*r0.x + Wl[j*6+1]*r0.y + Wl[j*6+2]*r0.z
                   + Wl[j*6+3]*r0.w + Wl[j*6+4]*r1.x + Wl[j*6+5]*r1.y;
  }
}

extern "C" void kernel_launch(void* const* d_in, const int* in_sizes, int n_in,
                              void* d_out, int out_size, void* d_ws, size_t ws_size,
                              hipStream_t stream)
{
  // setup_inputs order: 0 A_hat(unused) 1 X 2 W_ih 3 W_hh 4 b_ih 5 b_hh
  //                     6 Wf1 7 bf1 8 Wf2 9 bf2 10 Wf3 11 bf3 12 W_lean 13 b_lean
  const float* X    = (const float*)d_in[1];
  const float* Wih  = (const float*)d_in[2];
  const float* Whh  = (const float*)d_in[3];
  const float* bih  = (const float*)d_in[4];
  const float* bhh  = (const float*)d_in[5];
  const float* Wf1  = (const float*)d_in[6];
  const float* bf1  = (const float*)d_in[7];
  const float* Wf2  = (const float*)d_in[8];
  const float* bf2  = (const float*)d_in[9];
  const float* Wf3  = (const float*)d_in[10];
  const float* bf3  = (const float*)d_in[11];
  const float* Wl   = (const float*)d_in[12];
  const float* bl   = (const float*)d_in[13];
  float* out = (float*)d_out;
  float* ws  = (float*)d_ws;

  const bool packed = (ws_size >= 60000*sizeof(float));
  if (packed)
    hipLaunchKernelGGL(pack_weights, dim3(235), dim3(256), 0, stream, Wf1, Wf2, Wf3, ws);

  // LSTM writes al[s][n][j] (S*50*6 floats == out_size) into d_out as scratch.
  hipLaunchKernelGGL(lstm_kernel, dim3(CHUNKS), dim3(256), 0, stream,
                     X, Wih, Whh, bih, bhh, out);

  // Conv stack reads its al tile from d_out into LDS, then overwrites the same range.
  if (packed)
    hipLaunchKernelGGL((conv_kernel<true>), dim3(6144), dim3(256), 0, stream,
                       out, ws, bf1, ws+15000, bf2, ws+45000, bf3, Wl, bl);
  else
    hipLaunchKernelGGL((conv_kernel<false>), dim3(6144), dim3(256), 0, stream,
                       out, Wf1, bf1, Wf2, bf2, Wf3, bf3, Wl, bl);
}

// Round 2
// 615.367 us; speedup vs baseline: 1.5826x; 1.5826x over previous
//
#include <hip/hip_runtime.h>

#define CHUNKS 512
#define CHUNK_L 96
#define WARM 96

typedef short bf8_t __attribute__((ext_vector_type(8)));   // 8 bf16 in 4 VGPRs
typedef float f32x4 __attribute__((ext_vector_type(4)));

#define ROWB 256          // bytes per LDS row (128 bf16 / 64 f32)
#define BUFB 17408        // 68 rows * 256 B
// LDS regions: B0hi=0  B0lo=17408  B1hi=34816  B1lo=52224  (total 69632)

__device__ __forceinline__ int swz(int srow, int b){ return srow*ROWB + (b ^ ((srow&7)<<4)); }

__device__ __forceinline__ unsigned short f2bf(float x){
  unsigned u = __builtin_bit_cast(unsigned, x);
  unsigned r = (u + 0x7FFFu + ((u>>16)&1u)) >> 16;           // RNE
  return (unsigned short)r;
}
__device__ __forceinline__ float bf2f(unsigned short h){
  unsigned u = ((unsigned)h) << 16;
  return __builtin_bit_cast(float, u);
}

__device__ __forceinline__ float rcp_(float x){ return __builtin_amdgcn_rcpf(x); }
__device__ __forceinline__ float tanh_(float z){ return 1.f - 2.f*rcp_(1.f + __expf(2.f*z)); }

// ---------------- kernel 0: pack conv weights as MFMA B-fragments (hi/lo bf16) ----------
// frag order: L1 (d:3, ks:2, nt:7) -> 42 | L2 (d:3, ks:4, nt:7) -> 84 | L3 (d:3, ks:4, nt:4) -> 48
// ws ushort layout: [f][which(hi=0,lo=1)][lane][slot8]  => idx = f*1024 + which*512 + l*8 + j
__global__ void pack_frags(const float* __restrict__ W1, const float* __restrict__ W2,
                           const float* __restrict__ W3, unsigned short* __restrict__ ws)
{
  int tid = blockIdx.x*256 + threadIdx.x;
  if (tid >= 174*1024) return;
  int f = tid >> 10, rem = tid & 1023;
  int which = rem >> 9, e = rem & 511, l = e >> 3, j = e & 7;
  int d, ks, nt, I, O; const float* W;
  if (f < 42)      { int x = f;      d = x/14; ks = (x/7)%2; nt = x%7; I = 50;  O = 100; W = W1; }
  else if (f < 126){ int x = f-42;   d = x/28; ks = (x/7)%4; nt = x%7; I = 100; O = 100; W = W2; }
  else             { int x = f-126;  d = x/16; ks = (x/4)%4; nt = x%4; I = 100; O = 50;  W = W3; }
  int k = ks*32 + ((l>>4)<<3) + j;
  int o = nt*16 + (l&15);
  float v = (k < I && o < O) ? W[((o*I + k)*3 + d)*3 + 1] : 0.f;
  unsigned short hb = f2bf(v);
  float lo = v - bf2f(hb);
  ws[tid] = which ? f2bf(lo) : hb;
}

// ---------------- kernel 1: chunked LSTM scan (unchanged from R1) ----------------
__global__ __launch_bounds__(256,2) void lstm_kernel(
    const float* __restrict__ X, const float* __restrict__ Wih,
    const float* __restrict__ Whh, const float* __restrict__ bih,
    const float* __restrict__ bhh, float* __restrict__ al)
{
  __shared__ float h_s[50][8];
  __shared__ float g_s[50][25];
  const int t = threadIdx.x;
  const int c = blockIdx.x;
  const int s_begin = c*CHUNK_L;
  const int s_start = (s_begin >= WARM) ? (s_begin - WARM) : 0;
  const int s_end = s_begin + CHUNK_L;

  const bool isA = (t < 200);
  const int an = t % 50;
  const int ag = t / 50;

  float wih[6][12], whh[6][6], bs[6];
  if (isA){
    #pragma unroll
    for (int j=0;j<6;j++){
      const int r = ag*6 + j;
      #pragma unroll
      for (int k=0;k<12;k++) wih[j][k] = Wih[r*12+k];
      #pragma unroll
      for (int k=0;k<6;k++)  whh[j][k] = Whh[r*6+k];
      bs[j] = bih[r] + bhh[r];
    }
  }

  const int bn1 = t/6, bj1 = t%6;
  const int e2 = t + 256;
  const bool hasE2 = (e2 < 300);
  const int bn2 = e2/6, bj2 = e2%6;
  float c1 = 0.f, c2 = 0.f;

  for (int idx=t; idx<50*8; idx+=256) ((float*)h_s)[idx] = 0.f;
  __syncthreads();

  float4 xv0, xv1, xv2;
  float4 xn0 = {0,0,0,0}, xn1 = {0,0,0,0}, xn2 = {0,0,0,0};
  if (isA){
    const float4* xp = (const float4*)(X + (size_t)s_start*600 + an*12);
    xv0 = xp[0]; xv1 = xp[1]; xv2 = xp[2];
  }

  for (int s = s_start; s < s_end; ++s){
    if (isA){
      const float xr[12] = {xv0.x,xv0.y,xv0.z,xv0.w, xv1.x,xv1.y,xv1.z,xv1.w,
                            xv2.x,xv2.y,xv2.z,xv2.w};
      const float4 h03 = *(const float4*)&h_s[an][0];
      const float2 h45 = *(const float2*)&h_s[an][4];
      const float hr[6] = {h03.x,h03.y,h03.z,h03.w,h45.x,h45.y};
      #pragma unroll
      for (int j=0;j<6;j++){
        float a = bs[j];
        #pragma unroll
        for (int k=0;k<12;k++) a += wih[j][k]*xr[k];
        #pragma unroll
        for (int k=0;k<6;k++)  a += whh[j][k]*hr[k];
        const float zz = (ag==2) ? (a+a) : a;
        const float r = rcp_(1.f + __expf(-zz));
        g_s[an][ag*6+j] = (ag==2) ? (r+r-1.f) : r;
      }
      if (s+1 < s_end){
        const float4* xp = (const float4*)(X + (size_t)(s+1)*600 + an*12);
        xn0 = xp[0]; xn1 = xp[1]; xn2 = xp[2];
      }
    }
    __syncthreads();
    {
      const float gi = g_s[bn1][bj1], gf = g_s[bn1][6+bj1],
                  gg = g_s[bn1][12+bj1], go = g_s[bn1][18+bj1];
      c1 = gf*c1 + gi*gg;
      const float hn = tanh_(go * tanh_(c1));
      h_s[bn1][bj1] = hn;
      float hn2 = 0.f;
      if (hasE2){
        const float gi2 = g_s[bn2][bj2], gf2 = g_s[bn2][6+bj2],
                    gg2 = g_s[bn2][12+bj2], go2 = g_s[bn2][18+bj2];
        c2 = gf2*c2 + gi2*gg2;
        hn2 = tanh_(go2 * tanh_(c2));
        h_s[bn2][bj2] = hn2;
      }
      if (s >= s_begin){
        al[(size_t)s*300 + t] = hn;
        if (hasE2) al[(size_t)s*300 + e2] = hn2;
      }
    }
    __syncthreads();
    if (isA){ xv0=xn0; xv1=xn1; xv2=xn2; }
  }
}

// ---------------- kernel 2: MFMA conv x3 + lean, in-place on d_out --------------------
// One layer = 3 accumulating GEMM passes (d = 0..2) on a row-shifted A.
template<int KS, int NT, bool LAST>
__device__ __forceinline__ void conv_layer_mfma(
    char* lds, int inOff, int outOff, const unsigned short* __restrict__ wsU,
    int fbase, const float* __restrict__ bias, int O, int m0, int lane)
{
  f32x4 acc[NT];
  #pragma unroll
  for (int n=0;n<NT;n++) acc[n] = (f32x4){0.f,0.f,0.f,0.f};

  for (int d=0; d<3; ++d){
    const int arow = m0 + (lane & 15) + d;            // stored A row (logical + 1 - 1 + d)
    #pragma unroll
    for (int ks=0; ks<KS; ++ks){
      const int abyte = ks*64 + ((lane>>4)<<4);       // 16B-aligned; k = ks*32 + g*8 + j
      const bf8_t ah = *(const bf8_t*)(lds + inOff        + swz(arow, abyte));
      const bf8_t av = *(const bf8_t*)(lds + inOff + BUFB + swz(arow, abyte));
      const int f0 = fbase + (d*KS + ks)*NT;
      bf8_t bh[NT], bl[NT];
      #pragma unroll
      for (int n=0;n<NT;n++){
        const unsigned short* p = wsU + ((f0 + n) << 10) + (lane << 3);
        bh[n] = *(const bf8_t*)(p);
        bl[n] = *(const bf8_t*)(p + 512);
      }
      #pragma unroll
      for (int n=0;n<NT;n++){
        acc[n] = __builtin_amdgcn_mfma_f32_16x16x32_bf16(ah, bh[n], acc[n], 0, 0, 0);
        acc[n] = __builtin_amdgcn_mfma_f32_16x16x32_bf16(av, bh[n], acc[n], 0, 0, 0);
        acc[n] = __builtin_amdgcn_mfma_f32_16x16x32_bf16(ah, bl[n], acc[n], 0, 0, 0);
      }
    }
  }

  const int colBase = lane & 15;
  #pragma unroll
  for (int n=0;n<NT;n++){
    const int col = n*16 + colBase;
    const float b = (col < O) ? bias[col] : 0.f;
    #pragma unroll
    for (int r=0;r<4;r++){
      const int crow = m0 + ((lane>>4)<<2) + r;       // logical C row
      const int p8 = crow & 7;
      if (p8 >= 1 && p8 <= 6){
        const float v = fmaxf(acc[n][r] + b, 0.f);
        const int srow = crow + 1;
        if (LAST){
          *(float*)(lds + outOff + swz(srow, col*4)) = v;
        } else {
          const unsigned short hb = f2bf(v);
          *(unsigned short*)(lds + outOff        + swz(srow, col*2)) = hb;
          *(unsigned short*)(lds + outOff + BUFB + swz(srow, col*2)) = f2bf(v - bf2f(hb));
        }
      }
    }
  }
}

__global__ __launch_bounds__(256,2) void conv_mfma_kernel(
    float* __restrict__ io, const unsigned short* __restrict__ wsU,
    const float* __restrict__ b1, const float* __restrict__ b2, const float* __restrict__ b3,
    const float* __restrict__ Wl, const float* __restrict__ bl)
{
  __shared__ __align__(16) char lds[4*BUFB];
  const int t = threadIdx.x;
  const int lane = t & 63, w = t >> 6;
  const size_t base = (size_t)blockIdx.x * 2400;

  for (int i = t; i < (4*BUFB)/16; i += 256) ((f32x4*)lds)[i] = (f32x4){0.f,0.f,0.f,0.f};
  __syncthreads();

  // stage al tile -> B0 (hi/lo bf16), rows: stored = s*8 + y + 2, pads stay zero
  for (int idx = t; idx < 2400; idx += 256){
    const float v = io[base + idx];
    const int s = idx/300, rr = idx%300;
    const int ch = rr/6, y = rr%6;
    const int srow = s*8 + y + 2;
    const unsigned short hb = f2bf(v);
    *(unsigned short*)(lds        + swz(srow, ch*2)) = hb;
    *(unsigned short*)(lds + BUFB + swz(srow, ch*2)) = f2bf(v - bf2f(hb));
  }
  __syncthreads();

  conv_layer_mfma<2,7,false>(lds, 0,     34816, wsU, 0,   b1, 100, w*16, lane);
  __syncthreads();
  conv_layer_mfma<4,7,false>(lds, 34816, 0,     wsU, 42,  b2, 100, w*16, lane);
  __syncthreads();
  conv_layer_mfma<4,4,true >(lds, 0,     34816, wsU, 126, b3, 50,  w*16, lane);   // f32 into B1hi region
  __syncthreads();

  // lean: out[s][n][j] = bl[j] + sum_y Wl[j][y] * f[s][y][n]
  for (int idx = t; idx < 2400; idx += 256){
    const int s = idx/300, rr = idx%300;
    const int n = rr/6, j = rr%6;
    float sum = bl[j];
    #pragma unroll
    for (int y=0; y<6; y++)
      sum += Wl[j*6+y] * (*(const float*)(lds + 34816 + swz(s*8 + y + 2, n*4)));
    io[base + idx] = sum;
  }
}

// ---------------- fallback conv (raw weights, VALU) — used only if ws is too small ----
__device__ __forceinline__ float wraw(const float* __restrict__ W, int I, int i, int d, int o){
  return W[((o*I + i)*3 + d)*3 + 1];
}
template<int NS>
__device__ void conv_layer_valu(const float (* __restrict__ in)[100][8],
                                float (* __restrict__ outb)[100][8],
                                int I, const float* __restrict__ W,
                                const float* __restrict__ bias, int o, int s0)
{
  float acc[NS][6];
  const float b = bias[o];
  #pragma unroll
  for (int s=0;s<NS;s++)
    #pragma unroll
    for (int y=0;y<6;y++) acc[s][y]=b;
  for (int i=0;i<I;i++){
    const float w0 = wraw(W,I,i,0,o), w1 = wraw(W,I,i,1,o), w2 = wraw(W,I,i,2,o);
    #pragma unroll
    for (int s=0;s<NS;s++){
      const float4 r0 = *(const float4*)&in[s0+s][i][0];
      const float4 r1 = *(const float4*)&in[s0+s][i][4];
      acc[s][0] += w1*r0.x + w2*r0.y;
      acc[s][1] += w0*r0.x + w1*r0.y + w2*r0.z;
      acc[s][2] += w0*r0.y + w1*r0.z + w2*r0.w;
      acc[s][3] += w0*r0.z + w1*r0.w + w2*r1.x;
      acc[s][4] += w0*r0.w + w1*r1.x + w2*r1.y;
      acc[s][5] += w0*r1.x + w1*r1.y;
    }
  }
  #pragma unroll
  for (int s=0;s<NS;s++){
    float4 v0; float2 v1;
    v0.x = fmaxf(acc[s][0],0.f); v0.y = fmaxf(acc[s][1],0.f);
    v0.z = fmaxf(acc[s][2],0.f); v0.w = fmaxf(acc[s][3],0.f);
    v1.x = fmaxf(acc[s][4],0.f); v1.y = fmaxf(acc[s][5],0.f);
    *(float4*)&outb[s0+s][o][0] = v0;
    *(float2*)&outb[s0+s][o][4] = v1;
  }
}
__global__ __launch_bounds__(256,1) void conv_kernel_fb(
    float* __restrict__ io,
    const float* __restrict__ W1, const float* __restrict__ b1,
    const float* __restrict__ W2, const float* __restrict__ b2,
    const float* __restrict__ W3, const float* __restrict__ b3,
    const float* __restrict__ Wl, const float* __restrict__ bl)
{
  __shared__ float A[8][100][8];
  __shared__ float B[8][100][8];
  const int t = threadIdx.x;
  const size_t base = (size_t)blockIdx.x * 2400;
  for (int idx=t; idx<800; idx+=256){
    const int s = idx/100, ch = idx%100;
    A[s][ch][6]=0.f; A[s][ch][7]=0.f; B[s][ch][6]=0.f; B[s][ch][7]=0.f;
  }
  for (int idx=t; idx<2400; idx+=256){
    const float v = io[base + idx];
    const int s = idx/300, rr = idx%300;
    A[s][rr/6][rr%6] = v;
  }
  __syncthreads();
  const int w = t>>6, lane = t&63;
  { const int sh = w>>1, o = (w&1)*50 + lane;
    if (lane < 50) conv_layer_valu<4>(A, B, 50, W1, b1, o, sh*4); }
  __syncthreads();
  { const int sh = w>>1, o = (w&1)*50 + lane;
    if (lane < 50) conv_layer_valu<4>(B, A, 100, W2, b2, o, sh*4); }
  __syncthreads();
  { if (lane < 50) conv_layer_valu<2>(A, B, 100, W3, b3, lane, w*2); }
  __syncthreads();
  for (int idx=t; idx<2400; idx+=256){
    const int s = idx/300, rr = idx%300, n = rr/6, j = rr%6;
    const float4 r0 = *(const float4*)&B[s][n][0];
    const float2 r1 = *(const float2*)&B[s][n][4];
    io[base + idx] = bl[j] + Wl[j*6+0]*r0.x + Wl[j*6+1]*r0.y + Wl[j*6+2]*r0.z
                   + Wl[j*6+3]*r0.w + Wl[j*6+4]*r1.x + Wl[j*6+5]*r1.y;
  }
}

extern "C" void kernel_launch(void* const* d_in, const int* in_sizes, int n_in,
                              void* d_out, int out_size, void* d_ws, size_t ws_size,
                              hipStream_t stream)
{
  const float* X    = (const float*)d_in[1];
  const float* Wih  = (const float*)d_in[2];
  const float* Whh  = (const float*)d_in[3];
  const float* bih  = (const float*)d_in[4];
  const float* bhh  = (const float*)d_in[5];
  const float* Wf1  = (const float*)d_in[6];
  const float* bf1  = (const float*)d_in[7];
  const float* Wf2  = (const float*)d_in[8];
  const float* bf2  = (const float*)d_in[9];
  const float* Wf3  = (const float*)d_in[10];
  const float* bf3  = (const float*)d_in[11];
  const float* Wl   = (const float*)d_in[12];
  const float* bl   = (const float*)d_in[13];
  float* out = (float*)d_out;

  const bool packed = (ws_size >= 174*1024*sizeof(unsigned short));
  if (packed)
    hipLaunchKernelGGL(pack_frags, dim3(696), dim3(256), 0, stream,
                       Wf1, Wf2, Wf3, (unsigned short*)d_ws);

  hipLaunchKernelGGL(lstm_kernel, dim3(CHUNKS), dim3(256), 0, stream,
                     X, Wih, Whh, bih, bhh, out);

  if (packed)
    hipLaunchKernelGGL(conv_mfma_kernel, dim3(6144), dim3(256), 0, stream,
                       out, (const unsigned short*)d_ws, bf1, bf2, bf3, Wl, bl);
  else
    hipLaunchKernelGGL(conv_kernel_fb, dim3(6144), dim3(256), 0, stream,
                       out, Wf1, bf1, Wf2, bf2, Wf3, bf3, Wl, bl);
}

// Round 3
// 612.605 us; speedup vs baseline: 1.5897x; 1.0045x over previous
//
#include <hip/hip_runtime.h>

#define CHUNKS 512
#define CHUNK_L 96
#define WARM 96

typedef short bf8_t __attribute__((ext_vector_type(8)));   // 8 bf16 in 4 VGPRs
typedef float f32x4 __attribute__((ext_vector_type(4)));

#define ROWB 256          // bytes per LDS row (128 bf16 / 64 f32)
#define BUFB 17408        // 68 rows * 256 B
// LDS regions: B0hi=0  B0lo=17408  B1hi=34816  B1lo=52224  (total 69632)

__device__ __forceinline__ int swz(int srow, int b){ return srow*ROWB + (b ^ ((srow&7)<<4)); }

__device__ __forceinline__ unsigned short f2bf(float x){
  unsigned u = __builtin_bit_cast(unsigned, x);
  unsigned r = (u + 0x7FFFu + ((u>>16)&1u)) >> 16;           // RNE
  return (unsigned short)r;
}
__device__ __forceinline__ float bf2f(unsigned short h){
  unsigned u = ((unsigned)h) << 16;
  return __builtin_bit_cast(float, u);
}

__device__ __forceinline__ float rcp_(float x){ return __builtin_amdgcn_rcpf(x); }
__device__ __forceinline__ float tanh_(float z){ return 1.f - 2.f*rcp_(1.f + __expf(2.f*z)); }

// ---------------- kernel 0: pack conv weights as MFMA B-fragments (hi/lo bf16) ----------
// NEW layout: fragments contiguous per n-tile, so each nt's weight stream is one
// sequential 12-24 KB block:  frag index f = base + ((nt*3 + d)*KS + ks)*2 + which
//   L1: base 0,   NT=7, KS=2  -> 84 frags
//   L2: base 84,  NT=7, KS=4  -> 168 frags
//   L3: base 252, NT=4, KS=4  -> 96 frags   (total 348 frags * 512 ushort = 356352 B)
// ws ushort idx = f*512 + lane*8 + j ;  k = ks*32 + (lane>>4)*8 + j ; o = nt*16 + (lane&15)
__global__ void pack_frags(const float* __restrict__ W1, const float* __restrict__ W2,
                           const float* __restrict__ W3, unsigned short* __restrict__ ws)
{
  int tid = blockIdx.x*256 + threadIdx.x;
  if (tid >= 348*512) return;
  int f = tid >> 9, e = tid & 511, l = e >> 3, j = e & 7;
  int d, ks, nt, which, I, O; const float* W;
  if (f < 84)      { int x = f;     nt = x/12; int r = x%12; d = r/4;  ks = (r%4)>>1; which = r&1; I = 50;  O = 100; W = W1; }
  else if (f < 252){ int x = f-84;  nt = x/24; int r = x%24; d = r/8;  ks = (r%8)>>1; which = r&1; I = 100; O = 100; W = W2; }
  else             { int x = f-252; nt = x/24; int r = x%24; d = r/8;  ks = (r%8)>>1; which = r&1; I = 100; O = 50;  W = W3; }
  int k = ks*32 + ((l>>4)<<3) + j;
  int o = nt*16 + (l&15);
  float v = (k < I && o < O) ? W[((o*I + k)*3 + d)*3 + 1] : 0.f;
  unsigned short hb = f2bf(v);
  ws[tid] = which ? f2bf(v - bf2f(hb)) : hb;
}

// ---------------- kernel 1: chunked LSTM scan (unchanged) ----------------
__global__ __launch_bounds__(256,2) void lstm_kernel(
    const float* __restrict__ X, const float* __restrict__ Wih,
    const float* __restrict__ Whh, const float* __restrict__ bih,
    const float* __restrict__ bhh, float* __restrict__ al)
{
  __shared__ float h_s[50][8];
  __shared__ float g_s[50][25];
  const int t = threadIdx.x;
  const int c = blockIdx.x;
  const int s_begin = c*CHUNK_L;
  const int s_start = (s_begin >= WARM) ? (s_begin - WARM) : 0;
  const int s_end = s_begin + CHUNK_L;

  const bool isA = (t < 200);
  const int an = t % 50;
  const int ag = t / 50;

  float wih[6][12], whh[6][6], bs[6];
  if (isA){
    #pragma unroll
    for (int j=0;j<6;j++){
      const int r = ag*6 + j;
      #pragma unroll
      for (int k=0;k<12;k++) wih[j][k] = Wih[r*12+k];
      #pragma unroll
      for (int k=0;k<6;k++)  whh[j][k] = Whh[r*6+k];
      bs[j] = bih[r] + bhh[r];
    }
  }

  const int bn1 = t/6, bj1 = t%6;
  const int e2 = t + 256;
  const bool hasE2 = (e2 < 300);
  const int bn2 = e2/6, bj2 = e2%6;
  float c1 = 0.f, c2 = 0.f;

  for (int idx=t; idx<50*8; idx+=256) ((float*)h_s)[idx] = 0.f;
  __syncthreads();

  float4 xv0, xv1, xv2;
  float4 xn0 = {0,0,0,0}, xn1 = {0,0,0,0}, xn2 = {0,0,0,0};
  if (isA){
    const float4* xp = (const float4*)(X + (size_t)s_start*600 + an*12);
    xv0 = xp[0]; xv1 = xp[1]; xv2 = xp[2];
  }

  for (int s = s_start; s < s_end; ++s){
    if (isA){
      const float xr[12] = {xv0.x,xv0.y,xv0.z,xv0.w, xv1.x,xv1.y,xv1.z,xv1.w,
                            xv2.x,xv2.y,xv2.z,xv2.w};
      const float4 h03 = *(const float4*)&h_s[an][0];
      const float2 h45 = *(const float2*)&h_s[an][4];
      const float hr[6] = {h03.x,h03.y,h03.z,h03.w,h45.x,h45.y};
      #pragma unroll
      for (int j=0;j<6;j++){
        float a = bs[j];
        #pragma unroll
        for (int k=0;k<12;k++) a += wih[j][k]*xr[k];
        #pragma unroll
        for (int k=0;k<6;k++)  a += whh[j][k]*hr[k];
        const float zz = (ag==2) ? (a+a) : a;
        const float r = rcp_(1.f + __expf(-zz));
        g_s[an][ag*6+j] = (ag==2) ? (r+r-1.f) : r;
      }
      if (s+1 < s_end){
        const float4* xp = (const float4*)(X + (size_t)(s+1)*600 + an*12);
        xn0 = xp[0]; xn1 = xp[1]; xn2 = xp[2];
      }
    }
    __syncthreads();
    {
      const float gi = g_s[bn1][bj1], gf = g_s[bn1][6+bj1],
                  gg = g_s[bn1][12+bj1], go = g_s[bn1][18+bj1];
      c1 = gf*c1 + gi*gg;
      const float hn = tanh_(go * tanh_(c1));
      h_s[bn1][bj1] = hn;
      float hn2 = 0.f;
      if (hasE2){
        const float gi2 = g_s[bn2][bj2], gf2 = g_s[bn2][6+bj2],
                    gg2 = g_s[bn2][12+bj2], go2 = g_s[bn2][18+bj2];
        c2 = gf2*c2 + gi2*gg2;
        hn2 = tanh_(go2 * tanh_(c2));
        h_s[bn2][bj2] = hn2;
      }
      if (s >= s_begin){
        al[(size_t)s*300 + t] = hn;
        if (hasE2) al[(size_t)s*300 + e2] = hn2;
      }
    }
    __syncthreads();
    if (isA){ xv0=xn0; xv1=xn1; xv2=xn2; }
  }
}

// ---------------- kernel 2: MFMA conv x3 + lean, A register-resident -----------------
// Wave = one 16-row m-tile. A hi/lo fragments loaded ONCE per layer into registers;
// n-tile loop fully unrolled so the compiler overlaps nt+1's weight loads with
// nt's MFMA chain (36 MFMA ~ 180cy per nt covers the L2 latency).
template<int KS, int NT, bool LAST>
__device__ __forceinline__ void conv_layer_mfma(
    char* lds, int inOff, int outOff, const unsigned short* __restrict__ wsU,
    int fbase, const float* __restrict__ bias, int O, int m0, int lane)
{
  bf8_t ah[3][KS], av[3][KS];
  #pragma unroll
  for (int d=0; d<3; ++d){
    const int arow = m0 + (lane & 15) + d;
    #pragma unroll
    for (int ks=0; ks<KS; ++ks){
      const int abyte = ks*64 + ((lane>>4)<<4);
      ah[d][ks] = *(const bf8_t*)(lds + inOff        + swz(arow, abyte));
      av[d][ks] = *(const bf8_t*)(lds + inOff + BUFB + swz(arow, abyte));
    }
  }
  const int colBase = lane & 15;
  const int rbase = m0 + ((lane>>4)<<2);
  #pragma unroll
  for (int nt=0; nt<NT; ++nt){
    f32x4 acc = (f32x4){0.f,0.f,0.f,0.f};
    const unsigned short* pf = wsU + (size_t)(fbase + nt*(3*KS*2))*512 + (lane<<3);
    #pragma unroll
    for (int d=0; d<3; ++d){
      #pragma unroll
      for (int ks=0; ks<KS; ++ks){
        const bf8_t bh = *(const bf8_t*)(pf + ((d*KS+ks)*2  )*512);
        const bf8_t bl = *(const bf8_t*)(pf + ((d*KS+ks)*2+1)*512);
        acc = __builtin_amdgcn_mfma_f32_16x16x32_bf16(ah[d][ks], bh, acc, 0, 0, 0);
        acc = __builtin_amdgcn_mfma_f32_16x16x32_bf16(av[d][ks], bh, acc, 0, 0, 0);
        acc = __builtin_amdgcn_mfma_f32_16x16x32_bf16(ah[d][ks], bl, acc, 0, 0, 0);
      }
    }
    const int col = nt*16 + colBase;
    if (col < O){
      const float b = bias[col];
      #pragma unroll
      for (int r=0;r<4;r++){
        const int crow = rbase + r;
        const int p8 = crow & 7;
        if (p8 >= 1 && p8 <= 6){
          const float v = fmaxf(acc[r] + b, 0.f);
          const int srow = crow + 1;
          if (LAST){
            *(float*)(lds + outOff + swz(srow, col*4)) = v;
          } else {
            const unsigned short hb = f2bf(v);
            *(unsigned short*)(lds + outOff        + swz(srow, col*2)) = hb;
            *(unsigned short*)(lds + outOff + BUFB + swz(srow, col*2)) = f2bf(v - bf2f(hb));
          }
        }
      }
    }
  }
}

__global__ __launch_bounds__(256,2) void conv_mfma_kernel(
    float* __restrict__ io, const unsigned short* __restrict__ wsU,
    const float* __restrict__ b1, const float* __restrict__ b2, const float* __restrict__ b3,
    const float* __restrict__ Wl, const float* __restrict__ bl)
{
  __shared__ __align__(16) char lds[4*BUFB];
  const int t = threadIdx.x;
  const int lane = t & 63, w = t >> 6;
  const size_t base = (size_t)blockIdx.x * 2400;

  for (int i = t; i < (4*BUFB)/16; i += 256) ((f32x4*)lds)[i] = (f32x4){0.f,0.f,0.f,0.f};
  __syncthreads();

  // stage al tile -> B0 (hi/lo bf16), stored row = s*8 + y + 2, pad rows stay zero
  for (int idx = t; idx < 2400; idx += 256){
    const float v = io[base + idx];
    const int s = idx/300, rr = idx%300;
    const int ch = rr/6, y = rr%6;
    const int srow = s*8 + y + 2;
    const unsigned short hb = f2bf(v);
    *(unsigned short*)(lds        + swz(srow, ch*2)) = hb;
    *(unsigned short*)(lds + BUFB + swz(srow, ch*2)) = f2bf(v - bf2f(hb));
  }
  __syncthreads();

  conv_layer_mfma<2,7,false>(lds, 0,     34816, wsU, 0,   b1, 100, w*16, lane);
  __syncthreads();
  conv_layer_mfma<4,7,false>(lds, 34816, 0,     wsU, 84,  b2, 100, w*16, lane);
  __syncthreads();
  conv_layer_mfma<4,4,true >(lds, 0,     34816, wsU, 252, b3, 50,  w*16, lane);   // f32 into B1hi
  __syncthreads();

  // lean: out[s][n][j] = bl[j] + sum_y Wl[j][y] * f[s][y][n]
  for (int idx = t; idx < 2400; idx += 256){
    const int s = idx/300, rr = idx%300;
    const int n = rr/6, j = rr%6;
    float sum = bl[j];
    #pragma unroll
    for (int y=0; y<6; y++)
      sum += Wl[j*6+y] * (*(const float*)(lds + 34816 + swz(s*8 + y + 2, n*4)));
    io[base + idx] = sum;
  }
}

// ---------------- fallback conv (raw weights, VALU) — only if ws is too small --------
__device__ __forceinline__ float wraw(const float* __restrict__ W, int I, int i, int d, int o){
  return W[((o*I + i)*3 + d)*3 + 1];
}
template<int NS>
__device__ void conv_layer_valu(const float (* __restrict__ in)[100][8],
                                float (* __restrict__ outb)[100][8],
                                int I, const float* __restrict__ W,
                                const float* __restrict__ bias, int o, int s0)
{
  float acc[NS][6];
  const float b = bias[o];
  #pragma unroll
  for (int s=0;s<NS;s++)
    #pragma unroll
    for (int y=0;y<6;y++) acc[s][y]=b;
  for (int i=0;i<I;i++){
    const float w0 = wraw(W,I,i,0,o), w1 = wraw(W,I,i,1,o), w2 = wraw(W,I,i,2,o);
    #pragma unroll
    for (int s=0;s<NS;s++){
      const float4 r0 = *(const float4*)&in[s0+s][i][0];
      const float4 r1 = *(const float4*)&in[s0+s][i][4];
      acc[s][0] += w1*r0.x + w2*r0.y;
      acc[s][1] += w0*r0.x + w1*r0.y + w2*r0.z;
      acc[s][2] += w0*r0.y + w1*r0.z + w2*r0.w;
      acc[s][3] += w0*r0.z + w1*r0.w + w2*r1.x;
      acc[s][4] += w0*r0.w + w1*r1.x + w2*r1.y;
      acc[s][5] += w0*r1.x + w1*r1.y;
    }
  }
  #pragma unroll
  for (int s=0;s<NS;s++){
    float4 v0; float2 v1;
    v0.x = fmaxf(acc[s][0],0.f); v0.y = fmaxf(acc[s][1],0.f);
    v0.z = fmaxf(acc[s][2],0.f); v0.w = fmaxf(acc[s][3],0.f);
    v1.x = fmaxf(acc[s][4],0.f); v1.y = fmaxf(acc[s][5],0.f);
    *(float4*)&outb[s0+s][o][0] = v0;
    *(float2*)&outb[s0+s][o][4] = v1;
  }
}
__global__ __launch_bounds__(256,1) void conv_kernel_fb(
    float* __restrict__ io,
    const float* __restrict__ W1, const float* __restrict__ b1,
    const float* __restrict__ W2, const float* __restrict__ b2,
    const float* __restrict__ W3, const float* __restrict__ b3,
    const float* __restrict__ Wl, const float* __restrict__ bl)
{
  __shared__ float A[8][100][8];
  __shared__ float B[8][100][8];
  const int t = threadIdx.x;
  const size_t base = (size_t)blockIdx.x * 2400;
  for (int idx=t; idx<800; idx+=256){
    const int s = idx/100, ch = idx%100;
    A[s][ch][6]=0.f; A[s][ch][7]=0.f; B[s][ch][6]=0.f; B[s][ch][7]=0.f;
  }
  for (int idx=t; idx<2400; idx+=256){
    const float v = io[base + idx];
    const int s = idx/300, rr = idx%300;
    A[s][rr/6][rr%6] = v;
  }
  __syncthreads();
  const int w = t>>6, lane = t&63;
  { const int sh = w>>1, o = (w&1)*50 + lane;
    if (lane < 50) conv_layer_valu<4>(A, B, 50, W1, b1, o, sh*4); }
  __syncthreads();
  { const int sh = w>>1, o = (w&1)*50 + lane;
    if (lane < 50) conv_layer_valu<4>(B, A, 100, W2, b2, o, sh*4); }
  __syncthreads();
  { if (lane < 50) conv_layer_valu<2>(A, B, 100, W3, b3, lane, w*2); }
  __syncthreads();
  for (int idx=t; idx<2400; idx+=256){
    const int s = idx/300, rr = idx%300, n = rr/6, j = rr%6;
    const float4 r0 = *(const float4*)&B[s][n][0];
    const float2 r1 = *(const float2*)&B[s][n][4];
    io[base + idx] = bl[j] + Wl[j*6+0]*r0.x + Wl[j*6+1]*r0.y + Wl[j*6+2]*r0.z
                   + Wl[j*6+3]*r0.w + Wl[j*6+4]*r1.x + Wl[j*6+5]*r1.y;
  }
}

extern "C" void kernel_launch(void* const* d_in, const int* in_sizes, int n_in,
                              void* d_out, int out_size, void* d_ws, size_t ws_size,
                              hipStream_t stream)
{
  const float* X    = (const float*)d_in[1];
  const float* Wih  = (const float*)d_in[2];
  const float* Whh  = (const float*)d_in[3];
  const float* bih  = (const float*)d_in[4];
  const float* bhh  = (const float*)d_in[5];
  const float* Wf1  = (const float*)d_in[6];
  const float* bf1  = (const float*)d_in[7];
  const float* Wf2  = (const float*)d_in[8];
  const float* bf2  = (const float*)d_in[9];
  const float* Wf3  = (const float*)d_in[10];
  const float* bf3  = (const float*)d_in[11];
  const float* Wl   = (const float*)d_in[12];
  const float* bl   = (const float*)d_in[13];
  float* out = (float*)d_out;

  const bool packed = (ws_size >= 348*512*sizeof(unsigned short));
  if (packed)
    hipLaunchKernelGGL(pack_frags, dim3(696), dim3(256), 0, stream,
                       Wf1, Wf2, Wf3, (unsigned short*)d_ws);

  hipLaunchKernelGGL(lstm_kernel, dim3(CHUNKS), dim3(256), 0, stream,
                     X, Wih, Whh, bih, bhh, out);

  if (packed)
    hipLaunchKernelGGL(conv_mfma_kernel, dim3(6144), dim3(256), 0, stream,
                       out, (const unsigned short*)d_ws, bf1, bf2, bf3, Wl, bl);
  else
    hipLaunchKernelGGL(conv_kernel_fb, dim3(6144), dim3(256), 0, stream,
                       out, Wf1, bf1, Wf2, bf2, Wf3, bf3, Wl, bl);
}

// Round 4
// 362.044 us; speedup vs baseline: 2.6900x; 1.6921x over previous
//
#include <hip/hip_runtime.h>

#define CHUNKS 512
#define CHUNK_L 96
#define WARM 96

typedef _Float16 half8 __attribute__((ext_vector_type(8)));  // 8 f16 in 4 VGPRs
typedef float f32x4 __attribute__((ext_vector_type(4)));

#define ROWB 256          // bytes per LDS row (128 f16)
#define BUFB 17408        // 68 rows * 256 B
// LDS regions: buf0 = 0, buf1 = BUFB  (total 34816 B -> 4 blocks/CU)

__device__ __forceinline__ int swz(int srow, int b){ return srow*ROWB + (b ^ ((srow&7)<<4)); }

__device__ __forceinline__ unsigned short f2h_bits(float x){
  _Float16 h = (_Float16)x;
  return __builtin_bit_cast(unsigned short, h);
}

__device__ __forceinline__ float rcp_(float x){ return __builtin_amdgcn_rcpf(x); }
__device__ __forceinline__ float tanh_(float z){ return 1.f - 2.f*rcp_(1.f + __expf(2.f*z)); }

// ---------------- kernel 0: pack conv weights as f16 MFMA B-fragments ----------------
// frag index f = base + (d*KS + ks)*NT + nt   (weights for one (d,ks) step contiguous)
//   L1: base 0,   KS=2, NT=7 -> 42 | L2: base 42, KS=4, NT=7 -> 84 | L3: base 126, KS=4, NT=4 -> 48
// total 174 frags * 512 ushort = 178176 B
// ws ushort idx = f*512 + lane*8 + j ; k = ks*32 + (lane>>4)*8 + j ; o = nt*16 + (lane&15)
__global__ void pack_frags(const float* __restrict__ W1, const float* __restrict__ W2,
                           const float* __restrict__ W3, unsigned short* __restrict__ ws)
{
  int tid = blockIdx.x*256 + threadIdx.x;
  if (tid >= 174*512) return;
  int f = tid >> 9, e = tid & 511, l = e >> 3, j = e & 7;
  int d, ks, nt, I, O; const float* W;
  if (f < 42)      { int x = f;     int st = x/7;  nt = x%7; d = st/2; ks = st%2; I = 50;  O = 100; W = W1; }
  else if (f < 126){ int x = f-42;  int st = x/7;  nt = x%7; d = st/4; ks = st%4; I = 100; O = 100; W = W2; }
  else             { int x = f-126; int st = x/4;  nt = x%4; d = st/4; ks = st%4; I = 100; O = 50;  W = W3; }
  int k = ks*32 + ((l>>4)<<3) + j;
  int o = nt*16 + (l&15);
  float v = (k < I && o < O) ? W[((o*I + k)*3 + d)*3 + 1] : 0.f;
  ws[tid] = f2h_bits(v);
}

// ---------------- kernel 1: LSTM scan, 1 barrier/step, thread = state element --------
// t < 300 active: owns (n = t/6, j = t%6); computes its 4 gate rows {j,6+j,12+j,18+j}
// with weights in registers; h double-buffered in LDS.
__global__ __launch_bounds__(320,2) void lstm_kernel(
    const float* __restrict__ X, const float* __restrict__ Wih,
    const float* __restrict__ Whh, const float* __restrict__ bih,
    const float* __restrict__ bhh, float* __restrict__ al)
{
  __shared__ float h_s[2][50][6];
  const int t = threadIdx.x;
  const bool act = (t < 300);
  const int n = t/6, j = t%6;
  const int c = blockIdx.x;
  const int s_begin = c*CHUNK_L;
  const int s_start = (s_begin >= WARM) ? (s_begin - WARM) : 0;
  const int s_end = s_begin + CHUNK_L;

  float wi[4][12], wh[4][6], bb[4];
  if (act){
    #pragma unroll
    for (int g=0; g<4; ++g){
      const int r = g*6 + j;
      #pragma unroll
      for (int k=0;k<12;k++) wi[g][k] = Wih[r*12+k];
      #pragma unroll
      for (int k=0;k<6;k++)  wh[g][k] = Whh[r*6+k];
      bb[g] = bih[r] + bhh[r];
    }
  }
  for (int idx=t; idx<300; idx+=320) ((float*)h_s)[idx] = 0.f;  // h_s[0] = 0
  float cc = 0.f;

  float4 xv0={0,0,0,0}, xv1={0,0,0,0}, xv2={0,0,0,0};
  if (act){
    const float4* xp = (const float4*)(X + (size_t)s_start*600 + n*12);
    xv0 = xp[0]; xv1 = xp[1]; xv2 = xp[2];
  }
  __syncthreads();

  for (int s = s_start; s < s_end; ++s){
    const int p = (s - s_start) & 1;
    float hn = 0.f;
    float4 xn0, xn1, xn2;
    if (act){
      const float xr[12] = {xv0.x,xv0.y,xv0.z,xv0.w, xv1.x,xv1.y,xv1.z,xv1.w,
                            xv2.x,xv2.y,xv2.z,xv2.w};
      float a0 = bb[0], a1 = bb[1], a2 = bb[2], a3 = bb[3];
      #pragma unroll
      for (int k=0;k<12;k++){
        a0 += wi[0][k]*xr[k]; a1 += wi[1][k]*xr[k];
        a2 += wi[2][k]*xr[k]; a3 += wi[3][k]*xr[k];
      }
      if (s+1 < s_end){
        const float4* xp = (const float4*)(X + (size_t)(s+1)*600 + n*12);
        xn0 = xp[0]; xn1 = xp[1]; xn2 = xp[2];
      }
      const float2 h01 = *(const float2*)&h_s[p][n][0];
      const float2 h23 = *(const float2*)&h_s[p][n][2];
      const float2 h45 = *(const float2*)&h_s[p][n][4];
      const float hr[6] = {h01.x,h01.y,h23.x,h23.y,h45.x,h45.y};
      #pragma unroll
      for (int k=0;k<6;k++){
        a0 += wh[0][k]*hr[k]; a1 += wh[1][k]*hr[k];
        a2 += wh[2][k]*hr[k]; a3 += wh[3][k]*hr[k];
      }
      const float gi = rcp_(1.f + __expf(-a0));
      const float gf = rcp_(1.f + __expf(-a1));
      const float gg = 2.f*rcp_(1.f + __expf(-(a2+a2))) - 1.f;
      const float go = rcp_(1.f + __expf(-a3));
      cc = gf*cc + gi*gg;
      hn = tanh_(go * tanh_(cc));
      h_s[p^1][n][j] = hn;
      if (s >= s_begin) al[(size_t)s*300 + t] = hn;
      xv0 = xn0; xv1 = xn1; xv2 = xn2;
    }
    __syncthreads();
  }
}

// ---------------- kernel 2: f16 MFMA conv x3 + lean, ping-pong LDS -------------------
// (d,ks) outer, nt inner with acc[NT] live -> NT independent MFMA chains per wave.
template<int KS, int NT, bool LAST>
__device__ __forceinline__ void conv_layer_mfma(
    char* lds, int inOff, int outOff, const unsigned short* __restrict__ wsU,
    int fbase, const float* __restrict__ bias, int O, int m0, int lane)
{
  f32x4 acc[NT];
  #pragma unroll
  for (int nt=0;nt<NT;nt++) acc[nt] = (f32x4){0.f,0.f,0.f,0.f};

  const int arow_b = m0 + (lane & 15);
  const int abyte_g = (lane>>4)<<4;
  #pragma unroll
  for (int d=0; d<3; ++d){
    #pragma unroll
    for (int ks=0; ks<KS; ++ks){
      const half8 a = *(const half8*)(lds + inOff + swz(arow_b + d, ks*64 + abyte_g));
      const unsigned short* pf = wsU + (size_t)(fbase + (d*KS+ks)*NT)*512 + (lane<<3);
      #pragma unroll
      for (int nt=0; nt<NT; ++nt){
        const half8 b = *(const half8*)(pf + nt*512);
        acc[nt] = __builtin_amdgcn_mfma_f32_16x16x32_f16(a, b, acc[nt], 0, 0, 0);
      }
    }
  }

  const int colBase = lane & 15;
  const int rbase = m0 + ((lane>>4)<<2);
  #pragma unroll
  for (int nt=0; nt<NT; ++nt){
    const int col = nt*16 + colBase;
    if (col < O){
      const float b = bias[col];
      #pragma unroll
      for (int r=0;r<4;r++){
        const int crow = rbase + r;
        const int p8 = crow & 7;
        if (p8 >= 1 && p8 <= 6){
          const float v = fmaxf(acc[nt][r] + b, 0.f);
          const int srow = crow + 1;
          if (LAST) *(float*)(lds + outOff + swz(srow, col*4)) = v;
          else      *(unsigned short*)(lds + outOff + swz(srow, col*2)) = f2h_bits(v);
        }
      }
    }
  }
}

__global__ __launch_bounds__(256,4) void conv_mfma_kernel(
    float* __restrict__ io, const unsigned short* __restrict__ wsU,
    const float* __restrict__ b1, const float* __restrict__ b2, const float* __restrict__ b3,
    const float* __restrict__ Wl, const float* __restrict__ bl)
{
  __shared__ __align__(16) char lds[2*BUFB];
  const int t = threadIdx.x;
  const int lane = t & 63, w = t >> 6;
  const size_t base = (size_t)blockIdx.x * 2400;

  for (int i = t; i < (2*BUFB)/16; i += 256) ((f32x4*)lds)[i] = (f32x4){0.f,0.f,0.f,0.f};
  __syncthreads();

  // stage al tile -> buf0 as f16; stored row = s*8 + y + 2, pad rows stay zero
  for (int idx = t; idx < 2400; idx += 256){
    const float v = io[base + idx];
    const int s = idx/300, rr = idx%300;
    const int ch = rr/6, y = rr%6;
    *(unsigned short*)(lds + swz(s*8 + y + 2, ch*2)) = f2h_bits(v);
  }
  __syncthreads();

  conv_layer_mfma<2,7,false>(lds, 0,    BUFB, wsU, 0,   b1, 100, w*16, lane);
  __syncthreads();
  conv_layer_mfma<4,7,false>(lds, BUFB, 0,    wsU, 42,  b2, 100, w*16, lane);
  __syncthreads();
  conv_layer_mfma<4,4,true >(lds, 0,    BUFB, wsU, 126, b3, 50,  w*16, lane);   // f32 -> buf1
  __syncthreads();

  // lean: out[s][n][j] = bl[j] + sum_y Wl[j][y] * f[s][y][n]
  for (int idx = t; idx < 2400; idx += 256){
    const int s = idx/300, rr = idx%300;
    const int n = rr/6, j = rr%6;
    float sum = bl[j];
    #pragma unroll
    for (int y=0; y<6; y++)
      sum += Wl[j*6+y] * (*(const float*)(lds + BUFB + swz(s*8 + y + 2, n*4)));
    io[base + idx] = sum;
  }
}

// ---------------- fallback conv (raw weights, VALU) — only if ws too small -----------
__device__ __forceinline__ float wraw(const float* __restrict__ W, int I, int i, int d, int o){
  return W[((o*I + i)*3 + d)*3 + 1];
}
template<int NS>
__device__ void conv_layer_valu(const float (* __restrict__ in)[100][8],
                                float (* __restrict__ outb)[100][8],
                                int I, const float* __restrict__ W,
                                const float* __restrict__ bias, int o, int s0)
{
  float acc[NS][6];
  const float b = bias[o];
  #pragma unroll
  for (int s=0;s<NS;s++)
    #pragma unroll
    for (int y=0;y<6;y++) acc[s][y]=b;
  for (int i=0;i<I;i++){
    const float w0 = wraw(W,I,i,0,o), w1 = wraw(W,I,i,1,o), w2 = wraw(W,I,i,2,o);
    #pragma unroll
    for (int s=0;s<NS;s++){
      const float4 r0 = *(const float4*)&in[s0+s][i][0];
      const float4 r1 = *(const float4*)&in[s0+s][i][4];
      acc[s][0] += w1*r0.x + w2*r0.y;
      acc[s][1] += w0*r0.x + w1*r0.y + w2*r0.z;
      acc[s][2] += w0*r0.y + w1*r0.z + w2*r0.w;
      acc[s][3] += w0*r0.z + w1*r0.w + w2*r1.x;
      acc[s][4] += w0*r0.w + w1*r1.x + w2*r1.y;
      acc[s][5] += w0*r1.x + w1*r1.y;
    }
  }
  #pragma unroll
  for (int s=0;s<NS;s++){
    float4 v0; float2 v1;
    v0.x = fmaxf(acc[s][0],0.f); v0.y = fmaxf(acc[s][1],0.f);
    v0.z = fmaxf(acc[s][2],0.f); v0.w = fmaxf(acc[s][3],0.f);
    v1.x = fmaxf(acc[s][4],0.f); v1.y = fmaxf(acc[s][5],0.f);
    *(float4*)&outb[s0+s][o][0] = v0;
    *(float2*)&outb[s0+s][o][4] = v1;
  }
}
__global__ __launch_bounds__(256,1) void conv_kernel_fb(
    float* __restrict__ io,
    const float* __restrict__ W1, const float* __restrict__ b1,
    const float* __restrict__ W2, const float* __restrict__ b2,
    const float* __restrict__ W3, const float* __restrict__ b3,
    const float* __restrict__ Wl, const float* __restrict__ bl)
{
  __shared__ float A[8][100][8];
  __shared__ float B[8][100][8];
  const int t = threadIdx.x;
  const size_t base = (size_t)blockIdx.x * 2400;
  for (int idx=t; idx<800; idx+=256){
    const int s = idx/100, ch = idx%100;
    A[s][ch][6]=0.f; A[s][ch][7]=0.f; B[s][ch][6]=0.f; B[s][ch][7]=0.f;
  }
  for (int idx=t; idx<2400; idx+=256){
    const float v = io[base + idx];
    const int s = idx/300, rr = idx%300;
    A[s][rr/6][rr%6] = v;
  }
  __syncthreads();
  const int w = t>>6, lane = t&63;
  { const int sh = w>>1, o = (w&1)*50 + lane;
    if (lane < 50) conv_layer_valu<4>(A, B, 50, W1, b1, o, sh*4); }
  __syncthreads();
  { const int sh = w>>1, o = (w&1)*50 + lane;
    if (lane < 50) conv_layer_valu<4>(B, A, 100, W2, b2, o, sh*4); }
  __syncthreads();
  { if (lane < 50) conv_layer_valu<2>(A, B, 100, W3, b3, lane, w*2); }
  __syncthreads();
  for (int idx=t; idx<2400; idx+=256){
    const int s = idx/300, rr = idx%300, n = rr/6, j = rr%6;
    const float4 r0 = *(const float4*)&B[s][n][0];
    const float2 r1 = *(const float2*)&B[s][n][4];
    io[base + idx] = bl[j] + Wl[j*6+0]*r0.x + Wl[j*6+1]*r0.y + Wl[j*6+2]*r0.z
                   + Wl[j*6+3]*r0.w + Wl[j*6+4]*r1.x + Wl[j*6+5]*r1.y;
  }
}

extern "C" void kernel_launch(void* const* d_in, const int* in_sizes, int n_in,
                              void* d_out, int out_size, void* d_ws, size_t ws_size,
                              hipStream_t stream)
{
  const float* X    = (const float*)d_in[1];
  const float* Wih  = (const float*)d_in[2];
  const float* Whh  = (const float*)d_in[3];
  const float* bih  = (const float*)d_in[4];
  const float* bhh  = (const float*)d_in[5];
  const float* Wf1  = (const float*)d_in[6];
  const float* bf1  = (const float*)d_in[7];
  const float* Wf2  = (const float*)d_in[8];
  const float* bf2  = (const float*)d_in[9];
  const float* Wf3  = (const float*)d_in[10];
  const float* bf3  = (const float*)d_in[11];
  const float* Wl   = (const float*)d_in[12];
  const float* bl   = (const float*)d_in[13];
  float* out = (float*)d_out;

  const bool packed = (ws_size >= 174*512*sizeof(unsigned short));
  if (packed)
    hipLaunchKernelGGL(pack_frags, dim3(348), dim3(256), 0, stream,
                       Wf1, Wf2, Wf3, (unsigned short*)d_ws);

  hipLaunchKernelGGL(lstm_kernel, dim3(CHUNKS), dim3(320), 0, stream,
                     X, Wih, Whh, bih, bhh, out);

  if (packed)
    hipLaunchKernelGGL(conv_mfma_kernel, dim3(6144), dim3(256), 0, stream,
                       out, (const unsigned short*)d_ws, bf1, bf2, bf3, Wl, bl);
  else
    hipLaunchKernelGGL(conv_kernel_fb, dim3(6144), dim3(256), 0, stream,
                       out, Wf1, bf1, Wf2, bf2, Wf3, bf3, Wl, bl);
}

// Round 5
// 290.701 us; speedup vs baseline: 3.3501x; 1.2454x over previous
//
#include <hip/hip_runtime.h>

#define CHUNKS 512
#define CHUNK_L 96
#define WARM 48

typedef _Float16 half8 __attribute__((ext_vector_type(8)));  // 8 f16 in 4 VGPRs
typedef float f32x4 __attribute__((ext_vector_type(4)));

#define ROWB 256          // bytes per LDS row (128 f16)
#define BUFB 17408        // 68 rows * 256 B
// conv LDS regions: buf0 = 0, buf1 = BUFB  (total 34816 B -> 4 blocks/CU)

__device__ __forceinline__ int swz(int srow, int b){ return srow*ROWB + (b ^ ((srow&7)<<4)); }

__device__ __forceinline__ unsigned short f2h_bits(float x){
  _Float16 h = (_Float16)x;
  return __builtin_bit_cast(unsigned short, h);
}

__device__ __forceinline__ float rcp_(float x){ return __builtin_amdgcn_rcpf(x); }
__device__ __forceinline__ float tanh_(float z){ return 1.f - 2.f*rcp_(1.f + __expf(2.f*z)); }

// ---------------- kernel 0: pack conv weights as f16 MFMA B-fragments ----------------
// frag index f = base + (d*KS + ks)*NT + nt
//   L1: base 0, KS=2, NT=7 | L2: base 42, KS=4, NT=7 | L3: base 126, KS=4, NT=4
// ws ushort idx = f*512 + lane*8 + j ; k = ks*32 + (lane>>4)*8 + j ; o = nt*16 + (lane&15)
__global__ void pack_frags(const float* __restrict__ W1, const float* __restrict__ W2,
                           const float* __restrict__ W3, unsigned short* __restrict__ ws)
{
  int tid = blockIdx.x*256 + threadIdx.x;
  if (tid >= 174*512) return;
  int f = tid >> 9, e = tid & 511, l = e >> 3, j = e & 7;
  int d, ks, nt, I, O; const float* W;
  if (f < 42)      { int x = f;     int st = x/7;  nt = x%7; d = st/2; ks = st%2; I = 50;  O = 100; W = W1; }
  else if (f < 126){ int x = f-42;  int st = x/7;  nt = x%7; d = st/4; ks = st%4; I = 100; O = 100; W = W2; }
  else             { int x = f-126; int st = x/4;  nt = x%4; d = st/4; ks = st%4; I = 100; O = 50;  W = W3; }
  int k = ks*32 + ((l>>4)<<3) + j;
  int o = nt*16 + (l&15);
  float v = (k < I && o < O) ? W[((o*I + k)*3 + d)*3 + 1] : 0.f;
  ws[tid] = f2h_bits(v);
}

// ---------------- kernel 1: LSTM scan, lane = (node, element j), barrier-free --------
// Nodes are independent (gates touch only the node's own h). Lane l: q = l/6 (local
// node, 10 per wave), j = l%6. Lane holds gate rows {j,6+j,12+j,18+j} of its node:
// 72 weights in VGPRs, c_j in a register, full gate+state update in-lane. The only
// cross-lane traffic is broadcasting the node's 6 new h values: 6 ds_bpermute/step.
// 5 independent single-wave blocks per chunk -> no __syncthreads anywhere.
__global__ __launch_bounds__(64,3) void lstm_scan(
    const float* __restrict__ X, const float* __restrict__ Wih,
    const float* __restrict__ Whh, const float* __restrict__ bih,
    const float* __restrict__ bhh, float* __restrict__ al)
{
  const int l = threadIdx.x;
  const int blk = blockIdx.x;
  const int chunk = blk / 5, w = blk - chunk*5;   // w = 0..4 -> nodes w*10..w*10+9
  const int q = l / 6, j = l - q*6;               // q = 10 for idle lanes 60..63
  const bool active = (q < 10);
  const int n = w*10 + (active ? q : 0);
  const int sbase = active ? q*6 : 0;

  const int s_begin = chunk * CHUNK_L;
  const int s_start = (s_begin >= WARM) ? (s_begin - WARM) : 0;
  const int s_end   = s_begin + CHUNK_L;

  // per-lane weights: gate rows j (i), 6+j (f), 12+j (g), 18+j (o)
  float wi[4][12], wh[4][6], bb[4];
  #pragma unroll
  for (int g=0; g<4; ++g){
    const int r = g*6 + j;
    const float4 w0 = *(const float4*)(Wih + r*12);
    const float4 w1 = *(const float4*)(Wih + r*12 + 4);
    const float4 w2 = *(const float4*)(Wih + r*12 + 8);
    wi[g][0]=w0.x; wi[g][1]=w0.y; wi[g][2]=w0.z; wi[g][3]=w0.w;
    wi[g][4]=w1.x; wi[g][5]=w1.y; wi[g][6]=w1.z; wi[g][7]=w1.w;
    wi[g][8]=w2.x; wi[g][9]=w2.y; wi[g][10]=w2.z; wi[g][11]=w2.w;
    const float2 h0 = *(const float2*)(Whh + r*6);
    const float2 h1 = *(const float2*)(Whh + r*6 + 2);
    const float2 h2 = *(const float2*)(Whh + r*6 + 4);
    wh[g][0]=h0.x; wh[g][1]=h0.y; wh[g][2]=h1.x;
    wh[g][3]=h1.y; wh[g][4]=h2.x; wh[g][5]=h2.y;
    bb[g] = bih[r] + bhh[r];
  }

  float h[6];
  #pragma unroll
  for (int k=0;k<6;++k) h[k] = 0.f;
  float c = 0.f;

  const float* xp = X + (size_t)s_start*600 + n*12;
  float4 xa = ((const float4*)xp)[0];
  float4 xb = ((const float4*)xp)[1];
  float4 xc = ((const float4*)xp)[2];

  for (int s = s_start; s < s_end; ++s){
    const float xr[12] = {xa.x,xa.y,xa.z,xa.w, xb.x,xb.y,xb.z,xb.w,
                          xc.x,xc.y,xc.z,xc.w};
    const int sn = (s+1 < s_end) ? (s+1) : s;    // clamp: no UB, stays warm in L2
    const float* xq = X + (size_t)sn*600 + n*12;
    const float4 ya = ((const float4*)xq)[0];
    const float4 yb = ((const float4*)xq)[1];
    const float4 yc = ((const float4*)xq)[2];

    float a0 = bb[0], a1 = bb[1], a2 = bb[2], a3 = bb[3];
    #pragma unroll
    for (int k=0;k<12;++k){
      a0 += wi[0][k]*xr[k]; a1 += wi[1][k]*xr[k];
      a2 += wi[2][k]*xr[k]; a3 += wi[3][k]*xr[k];
    }
    #pragma unroll
    for (int k=0;k<6;++k){
      a0 += wh[0][k]*h[k]; a1 += wh[1][k]*h[k];
      a2 += wh[2][k]*h[k]; a3 += wh[3][k]*h[k];
    }
    const float gi = rcp_(1.f + __expf(-a0));
    const float gf = rcp_(1.f + __expf(-a1));
    const float gg = 2.f*rcp_(1.f + __expf(-(a2+a2))) - 1.f;
    const float go = rcp_(1.f + __expf(-a3));
    c = gf*c + gi*gg;
    const float hn = tanh_(go * tanh_(c));

    if (active && s >= s_begin) al[((size_t)s*50 + n)*6 + j] = hn;

    #pragma unroll
    for (int k=0;k<6;++k) h[k] = __shfl(hn, sbase + k, 64);

    xa = ya; xb = yb; xc = yc;
  }
}

// ---------------- kernel 2: f16 MFMA conv x3 + lean, ping-pong LDS -------------------
template<int KS, int NT, bool LAST>
__device__ __forceinline__ void conv_layer_mfma(
    char* lds, int inOff, int outOff, const unsigned short* __restrict__ wsU,
    int fbase, const float* __restrict__ bias, int O, int m0, int lane)
{
  f32x4 acc[NT];
  #pragma unroll
  for (int nt=0;nt<NT;nt++) acc[nt] = (f32x4){0.f,0.f,0.f,0.f};

  const int arow_b = m0 + (lane & 15);
  const int abyte_g = (lane>>4)<<4;
  #pragma unroll
  for (int d=0; d<3; ++d){
    #pragma unroll
    for (int ks=0; ks<KS; ++ks){
      const half8 a = *(const half8*)(lds + inOff + swz(arow_b + d, ks*64 + abyte_g));
      const unsigned short* pf = wsU + (size_t)(fbase + (d*KS+ks)*NT)*512 + (lane<<3);
      #pragma unroll
      for (int nt=0; nt<NT; ++nt){
        const half8 b = *(const half8*)(pf + nt*512);
        acc[nt] = __builtin_amdgcn_mfma_f32_16x16x32_f16(a, b, acc[nt], 0, 0, 0);
      }
    }
  }

  const int colBase = lane & 15;
  const int rbase = m0 + ((lane>>4)<<2);
  #pragma unroll
  for (int nt=0; nt<NT; ++nt){
    const int col = nt*16 + colBase;
    if (col < O){
      const float b = bias[col];
      #pragma unroll
      for (int r=0;r<4;r++){
        const int crow = rbase + r;
        const int p8 = crow & 7;
        if (p8 >= 1 && p8 <= 6){
          const float v = fmaxf(acc[nt][r] + b, 0.f);
          const int srow = crow + 1;
          if (LAST) *(float*)(lds + outOff + swz(srow, col*4)) = v;
          else      *(unsigned short*)(lds + outOff + swz(srow, col*2)) = f2h_bits(v);
        }
      }
    }
  }
}

__global__ __launch_bounds__(256,4) void conv_mfma_kernel(
    float* __restrict__ io, const unsigned short* __restrict__ wsU,
    const float* __restrict__ b1, const float* __restrict__ b2, const float* __restrict__ b3,
    const float* __restrict__ Wl, const float* __restrict__ bl)
{
  __shared__ __align__(16) char lds[2*BUFB];
  const int t = threadIdx.x;
  const int lane = t & 63, w = t >> 6;
  const size_t base = (size_t)blockIdx.x * 2400;

  for (int i = t; i < (2*BUFB)/16; i += 256) ((f32x4*)lds)[i] = (f32x4){0.f,0.f,0.f,0.f};
  __syncthreads();

  for (int idx = t; idx < 2400; idx += 256){
    const float v = io[base + idx];
    const int s = idx/300, rr = idx%300;
    const int ch = rr/6, y = rr%6;
    *(unsigned short*)(lds + swz(s*8 + y + 2, ch*2)) = f2h_bits(v);
  }
  __syncthreads();

  conv_layer_mfma<2,7,false>(lds, 0,    BUFB, wsU, 0,   b1, 100, w*16, lane);
  __syncthreads();
  conv_layer_mfma<4,7,false>(lds, BUFB, 0,    wsU, 42,  b2, 100, w*16, lane);
  __syncthreads();
  conv_layer_mfma<4,4,true >(lds, 0,    BUFB, wsU, 126, b3, 50,  w*16, lane);   // f32 -> buf1
  __syncthreads();

  for (int idx = t; idx < 2400; idx += 256){
    const int s = idx/300, rr = idx%300;
    const int n = rr/6, j = rr%6;
    float sum = bl[j];
    #pragma unroll
    for (int y=0; y<6; y++)
      sum += Wl[j*6+y] * (*(const float*)(lds + BUFB + swz(s*8 + y + 2, n*4)));
    io[base + idx] = sum;
  }
}

// ---------------- fallback conv (raw weights, VALU) — only if ws too small -----------
__device__ __forceinline__ float wraw(const float* __restrict__ W, int I, int i, int d, int o){
  return W[((o*I + i)*3 + d)*3 + 1];
}
template<int NS>
__device__ void conv_layer_valu(const float (* __restrict__ in)[100][8],
                                float (* __restrict__ outb)[100][8],
                                int I, const float* __restrict__ W,
                                const float* __restrict__ bias, int o, int s0)
{
  float acc[NS][6];
  const float b = bias[o];
  #pragma unroll
  for (int s=0;s<NS;s++)
    #pragma unroll
    for (int y=0;y<6;y++) acc[s][y]=b;
  for (int i=0;i<I;i++){
    const float w0 = wraw(W,I,i,0,o), w1 = wraw(W,I,i,1,o), w2 = wraw(W,I,i,2,o);
    #pragma unroll
    for (int s=0;s<NS;s++){
      const float4 r0 = *(const float4*)&in[s0+s][i][0];
      const float4 r1 = *(const float4*)&in[s0+s][i][4];
      acc[s][0] += w1*r0.x + w2*r0.y;
      acc[s][1] += w0*r0.x + w1*r0.y + w2*r0.z;
      acc[s][2] += w0*r0.y + w1*r0.z + w2*r0.w;
      acc[s][3] += w0*r0.z + w1*r0.w + w2*r1.x;
      acc[s][4] += w0*r0.w + w1*r1.x + w2*r1.y;
      acc[s][5] += w0*r1.x + w1*r1.y;
    }
  }
  #pragma unroll
  for (int s=0;s<NS;s++){
    float4 v0; float2 v1;
    v0.x = fmaxf(acc[s][0],0.f); v0.y = fmaxf(acc[s][1],0.f);
    v0.z = fmaxf(acc[s][2],0.f); v0.w = fmaxf(acc[s][3],0.f);
    v1.x = fmaxf(acc[s][4],0.f); v1.y = fmaxf(acc[s][5],0.f);
    *(float4*)&outb[s0+s][o][0] = v0;
    *(float2*)&outb[s0+s][o][4] = v1;
  }
}
__global__ __launch_bounds__(256,1) void conv_kernel_fb(
    float* __restrict__ io,
    const float* __restrict__ W1, const float* __restrict__ b1,
    const float* __restrict__ W2, const float* __restrict__ b2,
    const float* __restrict__ W3, const float* __restrict__ b3,
    const float* __restrict__ Wl, const float* __restrict__ bl)
{
  __shared__ float A[8][100][8];
  __shared__ float B[8][100][8];
  const int t = threadIdx.x;
  const size_t base = (size_t)blockIdx.x * 2400;
  for (int idx=t; idx<800; idx+=256){
    const int s = idx/100, ch = idx%100;
    A[s][ch][6]=0.f; A[s][ch][7]=0.f; B[s][ch][6]=0.f; B[s][ch][7]=0.f;
  }
  for (int idx=t; idx<2400; idx+=256){
    const float v = io[base + idx];
    const int s = idx/300, rr = idx%300;
    A[s][rr/6][rr%6] = v;
  }
  __syncthreads();
  const int w = t>>6, lane = t&63;
  { const int sh = w>>1, o = (w&1)*50 + lane;
    if (lane < 50) conv_layer_valu<4>(A, B, 50, W1, b1, o, sh*4); }
  __syncthreads();
  { const int sh = w>>1, o = (w&1)*50 + lane;
    if (lane < 50) conv_layer_valu<4>(B, A, 100, W2, b2, o, sh*4); }
  __syncthreads();
  { if (lane < 50) conv_layer_valu<2>(A, B, 100, W3, b3, lane, w*2); }
  __syncthreads();
  for (int idx=t; idx<2400; idx+=256){
    const int s = idx/300, rr = idx%300, n = rr/6, j = rr%6;
    const float4 r0 = *(const float4*)&B[s][n][0];
    const float2 r1 = *(const float2*)&B[s][n][4];
    io[base + idx] = bl[j] + Wl[j*6+0]*r0.x + Wl[j*6+1]*r0.y + Wl[j*6+2]*r0.z
                   + Wl[j*6+3]*r0.w + Wl[j*6+4]*r1.x + Wl[j*6+5]*r1.y;
  }
}

extern "C" void kernel_launch(void* const* d_in, const int* in_sizes, int n_in,
                              void* d_out, int out_size, void* d_ws, size_t ws_size,
                              hipStream_t stream)
{
  const float* X    = (const float*)d_in[1];
  const float* Wih  = (const float*)d_in[2];
  const float* Whh  = (const float*)d_in[3];
  const float* bih  = (const float*)d_in[4];
  const float* bhh  = (const float*)d_in[5];
  const float* Wf1  = (const float*)d_in[6];
  const float* bf1  = (const float*)d_in[7];
  const float* Wf2  = (const float*)d_in[8];
  const float* bf2  = (const float*)d_in[9];
  const float* Wf3  = (const float*)d_in[10];
  const float* bf3  = (const float*)d_in[11];
  const float* Wl   = (const float*)d_in[12];
  const float* bl   = (const float*)d_in[13];
  float* out = (float*)d_out;

  const bool packed = (ws_size >= 174*512*sizeof(unsigned short));
  if (packed)
    hipLaunchKernelGGL(pack_frags, dim3(348), dim3(256), 0, stream,
                       Wf1, Wf2, Wf3, (unsigned short*)d_ws);

  hipLaunchKernelGGL(lstm_scan, dim3(CHUNKS*5), dim3(64), 0, stream,
                     X, Wih, Whh, bih, bhh, out);

  if (packed)
    hipLaunchKernelGGL(conv_mfma_kernel, dim3(6144), dim3(256), 0, stream,
                       out, (const unsigned short*)d_ws, bf1, bf2, bf3, Wl, bl);
  else
    hipLaunchKernelGGL(conv_kernel_fb, dim3(6144), dim3(256), 0, stream,
                       out, Wf1, bf1, Wf2, bf2, Wf3, bf3, Wl, bl);
}

// Round 7
// 239.072 us; speedup vs baseline: 4.0736x; 1.2160x over previous
//
#include <hip/hip_runtime.h>

#define CHUNKS 512
#define CHUNK_L 96
#define WARM 48

typedef _Float16 half8 __attribute__((ext_vector_type(8)));  // 8 f16 in 4 VGPRs
typedef float f32x4 __attribute__((ext_vector_type(4)));

#define ROWB 256          // bytes per LDS row (128 f16)
#define BUFB 17408        // 68 rows * 256 B
// conv LDS regions: buf0 = 0, buf1 = BUFB  (total 34816 B -> 4 blocks/CU)

__device__ __forceinline__ int swz(int srow, int b){ return srow*ROWB + (b ^ ((srow&7)<<4)); }

__device__ __forceinline__ unsigned short f2h_bits(float x){
  _Float16 h = (_Float16)x;
  return __builtin_bit_cast(unsigned short, h);
}

__device__ __forceinline__ float rcp_(float x){ return __builtin_amdgcn_rcpf(x); }
__device__ __forceinline__ float tanh_(float z){ return 1.f - 2.f*rcp_(1.f + __expf(2.f*z)); }

// ---------------- kernel 0: pack conv weights as f16 MFMA B-fragments ----------------
// frag index f = base + (d*KS + ks)*NTT + nt
//   L1: base 0, KS=2, NTT=7 | L2: base 42, KS=4, NTT=7 | L3: base 126, KS=4, NTT=4
// ws ushort idx = f*512 + lane*8 + j ; k = ks*32 + (lane>>4)*8 + j ; o = nt*16 + (lane&15)
__global__ void pack_frags(const float* __restrict__ W1, const float* __restrict__ W2,
                           const float* __restrict__ W3, unsigned short* __restrict__ ws)
{
  int tid = blockIdx.x*256 + threadIdx.x;
  if (tid >= 174*512) return;
  int f = tid >> 9, e = tid & 511, l = e >> 3, j = e & 7;
  int d, ks, nt, I, O; const float* W;
  if (f < 42)      { int x = f;     int st = x/7;  nt = x%7; d = st/2; ks = st%2; I = 50;  O = 100; W = W1; }
  else if (f < 126){ int x = f-42;  int st = x/7;  nt = x%7; d = st/4; ks = st%4; I = 100; O = 100; W = W2; }
  else             { int x = f-126; int st = x/4;  nt = x%4; d = st/4; ks = st%4; I = 100; O = 50;  W = W3; }
  int k = ks*32 + ((l>>4)<<3) + j;
  int o = nt*16 + (l&15);
  float v = (k < I && o < O) ? W[((o*I + k)*3 + d)*3 + 1] : 0.f;
  ws[tid] = f2h_bits(v);
}

// ---------------- kernel 1: LSTM scan, lane = (node, element), depth-2 x prefetch ----
__global__ __launch_bounds__(64,3) void lstm_scan(
    const float* __restrict__ X, const float* __restrict__ Wih,
    const float* __restrict__ Whh, const float* __restrict__ bih,
    const float* __restrict__ bhh, float* __restrict__ al)
{
  const int l = threadIdx.x;
  const int blk = blockIdx.x;
  const int chunk = blk / 5, w = blk - chunk*5;
  const int q = l / 6, j = l - q*6;
  const bool active = (q < 10);
  const int n = w*10 + (active ? q : 0);
  const int sbase = active ? q*6 : 0;

  const int s_begin = chunk * CHUNK_L;
  const int s_start = (s_begin >= WARM) ? (s_begin - WARM) : 0;
  const int s_end   = s_begin + CHUNK_L;

  float wi[4][12], wh[4][6], bb[4];
  #pragma unroll
  for (int g=0; g<4; ++g){
    const int r = g*6 + j;
    const float4 w0 = *(const float4*)(Wih + r*12);
    const float4 w1 = *(const float4*)(Wih + r*12 + 4);
    const float4 w2 = *(const float4*)(Wih + r*12 + 8);
    wi[g][0]=w0.x; wi[g][1]=w0.y; wi[g][2]=w0.z; wi[g][3]=w0.w;
    wi[g][4]=w1.x; wi[g][5]=w1.y; wi[g][6]=w1.z; wi[g][7]=w1.w;
    wi[g][8]=w2.x; wi[g][9]=w2.y; wi[g][10]=w2.z; wi[g][11]=w2.w;
    const float2 h0 = *(const float2*)(Whh + r*6);
    const float2 h1 = *(const float2*)(Whh + r*6 + 2);
    const float2 h2 = *(const float2*)(Whh + r*6 + 4);
    wh[g][0]=h0.x; wh[g][1]=h0.y; wh[g][2]=h1.x;
    wh[g][3]=h1.y; wh[g][4]=h2.x; wh[g][5]=h2.y;
    bb[g] = bih[r] + bhh[r];
  }

  float h[6];
  #pragma unroll
  for (int k=0;k<6;++k) h[k] = 0.f;
  float c = 0.f;

  // x pipeline: xa = x[s], xb = x[s+1]; load x[s+2] at loop top
  const float* xp0 = X + (size_t)s_start*600 + n*12;
  float4 xa0 = ((const float4*)xp0)[0], xa1 = ((const float4*)xp0)[1], xa2 = ((const float4*)xp0)[2];
  const int s1 = (s_start+1 < s_end) ? s_start+1 : s_start;
  const float* xp1 = X + (size_t)s1*600 + n*12;
  float4 xb0 = ((const float4*)xp1)[0], xb1 = ((const float4*)xp1)[1], xb2 = ((const float4*)xp1)[2];

  for (int s = s_start; s < s_end; ++s){
    const int sn = (s+2 < s_end) ? (s+2) : (s_end-1);
    const float* xq = X + (size_t)sn*600 + n*12;
    const float4 xc0 = ((const float4*)xq)[0];
    const float4 xc1 = ((const float4*)xq)[1];
    const float4 xc2 = ((const float4*)xq)[2];

    const float xr[12] = {xa0.x,xa0.y,xa0.z,xa0.w, xa1.x,xa1.y,xa1.z,xa1.w,
                          xa2.x,xa2.y,xa2.z,xa2.w};
    float a0 = bb[0], a1 = bb[1], a2 = bb[2], a3 = bb[3];
    #pragma unroll
    for (int k=0;k<12;++k){
      a0 += wi[0][k]*xr[k]; a1 += wi[1][k]*xr[k];
      a2 += wi[2][k]*xr[k]; a3 += wi[3][k]*xr[k];
    }
    #pragma unroll
    for (int k=0;k<6;++k){
      a0 += wh[0][k]*h[k]; a1 += wh[1][k]*h[k];
      a2 += wh[2][k]*h[k]; a3 += wh[3][k]*h[k];
    }
    const float gi = rcp_(1.f + __expf(-a0));
    const float gf = rcp_(1.f + __expf(-a1));
    const float gg = 2.f*rcp_(1.f + __expf(-(a2+a2))) - 1.f;
    const float go = rcp_(1.f + __expf(-a3));
    c = gf*c + gi*gg;
    const float hn = tanh_(go * tanh_(c));

    if (active && s >= s_begin) al[(size_t)s*300 + n*6 + j] = hn;

    #pragma unroll
    for (int k=0;k<6;++k) h[k] = __shfl(hn, sbase + k, 64);

    xa0 = xb0; xa1 = xb1; xa2 = xb2;
    xb0 = xc0; xb1 = xc1; xb2 = xc2;
  }
}

// ---------------- kernel 2: f16 MFMA conv x3 + lean, 2 m-tiles/wave, n-split ---------
// Wave (mg,ng): rows [mg*32, mg*32+32), n-tiles [ntOff, ntOff+NTG). Register
// double-buffer on A (LDS) and B (global) so step st+1's loads overlap st's 2*NTG MFMAs.
template<int KS, int NTT, int NTG, bool LAST>
__device__ __forceinline__ void conv_layer2(
    char* lds, int inOff, int outOff, const unsigned short* __restrict__ wsU,
    int fbase, int ntOff, const float* __restrict__ bias, int O, int m0, int lane)
{
  f32x4 acc[2][NTG];
  #pragma unroll
  for (int m=0;m<2;m++)
    #pragma unroll
    for (int n=0;n<NTG;n++) acc[m][n] = (f32x4){0.f,0.f,0.f,0.f};

  const int ar = m0 + (lane & 15);
  const int abyte_g = (lane>>4)<<4;
  const int laneb = lane << 3;

  half8 a0c = *(const half8*)(lds + inOff + swz(ar, abyte_g));        // st=0: d=0,ks=0
  half8 a1c = *(const half8*)(lds + inOff + swz(ar + 16, abyte_g));
  half8 bc[NTG];
  {
    const unsigned short* p0 = wsU + (size_t)(fbase + ntOff)*512 + laneb;
    #pragma unroll
    for (int n=0;n<NTG;n++) bc[n] = *(const half8*)(p0 + n*512);
  }

  #pragma unroll
  for (int st=0; st<3*KS; ++st){
    half8 a0n, a1n, bn[NTG];
    if (st+1 < 3*KS){
      const int dn = (st+1)/KS, ksn = (st+1)%KS;
      a0n = *(const half8*)(lds + inOff + swz(ar + dn, ksn*64 + abyte_g));
      a1n = *(const half8*)(lds + inOff + swz(ar + 16 + dn, ksn*64 + abyte_g));
      const unsigned short* pn = wsU + (size_t)(fbase + (st+1)*NTT + ntOff)*512 + laneb;
      #pragma unroll
      for (int n=0;n<NTG;n++) bn[n] = *(const half8*)(pn + n*512);
    }
    #pragma unroll
    for (int n=0;n<NTG;n++){
      acc[0][n] = __builtin_amdgcn_mfma_f32_16x16x32_f16(a0c, bc[n], acc[0][n], 0, 0, 0);
      acc[1][n] = __builtin_amdgcn_mfma_f32_16x16x32_f16(a1c, bc[n], acc[1][n], 0, 0, 0);
    }
    if (st+1 < 3*KS){
      a0c = a0n; a1c = a1n;
      #pragma unroll
      for (int n=0;n<NTG;n++) bc[n] = bn[n];
    }
  }

  const int colBase = lane & 15;
  #pragma unroll
  for (int m=0;m<2;m++){
    const int rbase = m0 + m*16 + ((lane>>4)<<2);
    #pragma unroll
    for (int n=0;n<NTG;n++){
      const int col = (ntOff + n)*16 + colBase;
      if (col < O){
        const float b = bias[col];
        #pragma unroll
        for (int r=0;r<4;r++){
          const int crow = rbase + r;
          const int p8 = crow & 7;
          if (p8 >= 1 && p8 <= 6){
            const float v = fmaxf(acc[m][n][r] + b, 0.f);
            const int srow = crow + 1;
            if (LAST) *(float*)(lds + outOff + swz(srow, col*4)) = v;
            else      *(unsigned short*)(lds + outOff + swz(srow, col*2)) = f2h_bits(v);
          }
        }
      }
    }
  }
}

__global__ __launch_bounds__(256,4) void conv_mfma_kernel(
    float* __restrict__ io, const unsigned short* __restrict__ wsU,
    const float* __restrict__ b1, const float* __restrict__ b2, const float* __restrict__ b3,
    const float* __restrict__ Wl, const float* __restrict__ bl)
{
  __shared__ __align__(16) char lds[2*BUFB];
  const int t = threadIdx.x;
  const int lane = t & 63, w = t >> 6;
  const int mg = w >> 1, ng = w & 1;
  const int m0 = mg*32;
  const size_t base = (size_t)blockIdx.x * 2400;

  // Zero BOTH buffers fully. Data-row tail bytes (cols >= I) are swept by the padded
  // K-range A-reads; leftover LDS NaN/Inf there turns acc into NaN, and fmaxf(NaN,0)=0
  // silently corrupts outputs (R6 failure). Full zero guarantees garbage-free K-pad.
  for (int i = t; i < (2*BUFB)/16; i += 256) ((f32x4*)lds)[i] = (f32x4){0.f,0.f,0.f,0.f};
  __syncthreads();

  // stage al tile -> buf0 as f16; stored row = s*8 + y + 2, pad rows stay zero
  for (int idx = t; idx < 2400; idx += 256){
    const float v = io[base + idx];
    const int s = idx/300, rr = idx%300;
    const int ch = rr/6, y = rr%6;
    *(unsigned short*)(lds + swz(s*8 + y + 2, ch*2)) = f2h_bits(v);
  }
  __syncthreads();

  if (ng == 0) conv_layer2<2,7,4,false>(lds, 0,    BUFB, wsU, 0,   0, b1, 100, m0, lane);
  else         conv_layer2<2,7,3,false>(lds, 0,    BUFB, wsU, 0,   4, b1, 100, m0, lane);
  __syncthreads();
  if (ng == 0) conv_layer2<4,7,4,false>(lds, BUFB, 0,    wsU, 42,  0, b2, 100, m0, lane);
  else         conv_layer2<4,7,3,false>(lds, BUFB, 0,    wsU, 42,  4, b2, 100, m0, lane);
  __syncthreads();
  if (ng == 0) conv_layer2<4,4,2,true >(lds, 0,    BUFB, wsU, 126, 0, b3, 50,  m0, lane);
  else         conv_layer2<4,4,2,true >(lds, 0,    BUFB, wsU, 126, 2, b3, 50,  m0, lane);
  __syncthreads();

  // lean: out[s][n][j] = bl[j] + sum_y Wl[j][y] * f[s][y][n]   (f = f32 in buf1)
  for (int idx = t; idx < 2400; idx += 256){
    const int s = idx/300, rr = idx%300;
    const int n = rr/6, j = rr%6;
    float sum = bl[j];
    #pragma unroll
    for (int y=0; y<6; y++)
      sum += Wl[j*6+y] * (*(const float*)(lds + BUFB + swz(s*8 + y + 2, n*4)));
    io[base + idx] = sum;
  }
}

// ---------------- fallback conv (raw weights, VALU) — only if ws too small -----------
__device__ __forceinline__ float wraw(const float* __restrict__ W, int I, int i, int d, int o){
  return W[((o*I + i)*3 + d)*3 + 1];
}
template<int NS>
__device__ void conv_layer_valu(const float (* __restrict__ in)[100][8],
                                float (* __restrict__ outb)[100][8],
                                int I, const float* __restrict__ W,
                                const float* __restrict__ bias, int o, int s0)
{
  float acc[NS][6];
  const float b = bias[o];
  #pragma unroll
  for (int s=0;s<NS;s++)
    #pragma unroll
    for (int y=0;y<6;y++) acc[s][y]=b;
  for (int i=0;i<I;i++){
    const float w0 = wraw(W,I,i,0,o), w1 = wraw(W,I,i,1,o), w2 = wraw(W,I,i,2,o);
    #pragma unroll
    for (int s=0;s<NS;s++){
      const float4 r0 = *(const float4*)&in[s0+s][i][0];
      const float4 r1 = *(const float4*)&in[s0+s][i][4];
      acc[s][0] += w1*r0.x + w2*r0.y;
      acc[s][1] += w0*r0.x + w1*r0.y + w2*r0.z;
      acc[s][2] += w0*r0.y + w1*r0.z + w2*r0.w;
      acc[s][3] += w0*r0.z + w1*r0.w + w2*r1.x;
      acc[s][4] += w0*r0.w + w1*r1.x + w2*r1.y;
      acc[s][5] += w0*r1.x + w1*r1.y;
    }
  }
  #pragma unroll
  for (int s=0;s<NS;s++){
    float4 v0; float2 v1;
    v0.x = fmaxf(acc[s][0],0.f); v0.y = fmaxf(acc[s][1],0.f);
    v0.z = fmaxf(acc[s][2],0.f); v0.w = fmaxf(acc[s][3],0.f);
    v1.x = fmaxf(acc[s][4],0.f); v1.y = fmaxf(acc[s][5],0.f);
    *(float4*)&outb[s0+s][o][0] = v0;
    *(float2*)&outb[s0+s][o][4] = v1;
  }
}
__global__ __launch_bounds__(256,1) void conv_kernel_fb(
    float* __restrict__ io,
    const float* __restrict__ W1, const float* __restrict__ b1,
    const float* __restrict__ W2, const float* __restrict__ b2,
    const float* __restrict__ W3, const float* __restrict__ b3,
    const float* __restrict__ Wl, const float* __restrict__ bl)
{
  __shared__ float A[8][100][8];
  __shared__ float B[8][100][8];
  const int t = threadIdx.x;
  const size_t base = (size_t)blockIdx.x * 2400;
  for (int idx=t; idx<800; idx+=256){
    const int s = idx/100, ch = idx%100;
    A[s][ch][6]=0.f; A[s][ch][7]=0.f; B[s][ch][6]=0.f; B[s][ch][7]=0.f;
  }
  for (int idx=t; idx<2400; idx+=256){
    const float v = io[base + idx];
    const int s = idx/300, rr = idx%300;
    A[s][rr/6][rr%6] = v;
  }
  __syncthreads();
  const int w = t>>6, lane = t&63;
  { const int sh = w>>1, o = (w&1)*50 + lane;
    if (lane < 50) conv_layer_valu<4>(A, B, 50, W1, b1, o, sh*4); }
  __syncthreads();
  { const int sh = w>>1, o = (w&1)*50 + lane;
    if (lane < 50) conv_layer_valu<4>(B, A, 100, W2, b2, o, sh*4); }
  __syncthreads();
  { if (lane < 50) conv_layer_valu<2>(A, B, 100, W3, b3, lane, w*2); }
  __syncthreads();
  for (int idx=t; idx<2400; idx+=256){
    const int s = idx/300, rr = idx%300, n = rr/6, j = rr%6;
    const float4 r0 = *(const float4*)&B[s][n][0];
    const float2 r1 = *(const float2*)&B[s][n][4];
    io[base + idx] = bl[j] + Wl[j*6+0]*r0.x + Wl[j*6+1]*r0.y + Wl[j*6+2]*r0.z
                   + Wl[j*6+3]*r0.w + Wl[j*6+4]*r1.x + Wl[j*6+5]*r1.y;
  }
}

extern "C" void kernel_launch(void* const* d_in, const int* in_sizes, int n_in,
                              void* d_out, int out_size, void* d_ws, size_t ws_size,
                              hipStream_t stream)
{
  const float* X    = (const float*)d_in[1];
  const float* Wih  = (const float*)d_in[2];
  const float* Whh  = (const float*)d_in[3];
  const float* bih  = (const float*)d_in[4];
  const float* bhh  = (const float*)d_in[5];
  const float* Wf1  = (const float*)d_in[6];
  const float* bf1  = (const float*)d_in[7];
  const float* Wf2  = (const float*)d_in[8];
  const float* bf2  = (const float*)d_in[9];
  const float* Wf3  = (const float*)d_in[10];
  const float* bf3  = (const float*)d_in[11];
  const float* Wl   = (const float*)d_in[12];
  const float* bl   = (const float*)d_in[13];
  float* out = (float*)d_out;

  const bool packed = (ws_size >= 174*512*sizeof(unsigned short));
  if (packed)
    hipLaunchKernelGGL(pack_frags, dim3(348), dim3(256), 0, stream,
                       Wf1, Wf2, Wf3, (unsigned short*)d_ws);

  hipLaunchKernelGGL(lstm_scan, dim3(CHUNKS*5), dim3(64), 0, stream,
                     X, Wih, Whh, bih, bhh, out);

  if (packed)
    hipLaunchKernelGGL(conv_mfma_kernel, dim3(6144), dim3(256), 0, stream,
                       out, (const unsigned short*)d_ws, bf1, bf2, bf3, Wl, bl);
  else
    hipLaunchKernelGGL(conv_kernel_fb, dim3(6144), dim3(256), 0, stream,
                       out, Wf1, bf1, Wf2, bf2, Wf3, bf3, Wl, bl);
}